// Round 2
// baseline (13255.727 us; speedup 1.0000x reference)
//
#include <hip/hip_runtime.h>
#include <cstddef>

// ---------------- constants ----------------
__constant__ int c_PERM[25] = {0,2,6,12,20, 1,5,11,19, 3,7,13,21, 4,10,18, 8,14,22, 9,17, 15,23, 16,24};
__constant__ int c_ROFF[25] = {0,256,512,768,1024, 1280,1536,1792,2048, 1280,1536,1792,2048,
                               2304,2560,2816, 2304,2560,2816, 3072,3328, 3072,3328, 3584,3584};
__constant__ int c_EXPAND[25] = {0,1,1,1,2,2,2,2,2,3,3,3,3,3,3,3,4,4,4,4,4,4,4,4,4};

static constexpr int PERM_CE[25] = {0,2,6,12,20, 1,5,11,19, 3,7,13,21, 4,10,18, 8,14,22, 9,17, 15,23, 16,24};
static constexpr int INV_CE[25]  = {0,5,1,9,13, 6,2,10,16,19, 14,7,3,11,17, 21,23,20,15,8, 4,12,18,22,24};

__device__ __forceinline__ float wsum64(float v){
#pragma unroll
  for(int m=32;m>0;m>>=1) v += __shfl_xor(v, m, 64);
  return v;
}
__device__ __forceinline__ float siluf(float x){ return x/(1.f+expf(-x)); }

// ---------------- weight transform: complex block -> plain GEMM ----------------
__global__ __launch_bounds__(256) void wtrans_kernel(const float* __restrict__ W, float* __restrict__ W2, int K, int C2){
  int idx = blockIdx.x*256 + threadIdx.x;
  int total = 2*K*C2;
  if(idx>=total) return;
  int k2 = idx / C2, j = idx % C2;
  int half = C2>>1;
  float v;
  if(k2 < K) v = W[k2*C2 + j];
  else { int k = k2-K; v = (j<half) ? -W[k*C2 + half + j] : W[k*C2 + j - half]; }
  W2[idx] = v;
}

// proj_w (5,128o,128i) -> pwt (5,128i,128o)
__global__ __launch_bounds__(256) void ptrans_kernel(const float* __restrict__ pw, float* __restrict__ pwt){
  int idx = blockIdx.x*256+threadIdx.x;
  if(idx >= 5*16384) return;
  int l = idx>>14, r = idx & 16383, i = r>>7, o = r&127;
  pwt[idx] = pw[(l<<14) + (o<<7) + i];
}

// ---------------- radial MLP: 2 layers LN+silu -> h2 (C,64) ----------------
__global__ __launch_bounds__(64) void radial_kernel(
    const float* __restrict__ ed, const float* __restrict__ st, const float* __restrict__ tt,
    const float* __restrict__ w1, const float* __restrict__ b1, const float* __restrict__ g1, const float* __restrict__ bb1,
    const float* __restrict__ w2, const float* __restrict__ b2, const float* __restrict__ g2, const float* __restrict__ bb2,
    const int* __restrict__ an, const int* __restrict__ src, const int* __restrict__ tgt, float* __restrict__ h2out){
  int e = blockIdx.x; int lane = threadIdx.x;
  __shared__ float xe[256];
  __shared__ float h1s[64];
  int s = src[e], t = tgt[e];
  xe[lane]      = ed[(size_t)e*128 + lane];
  xe[64+lane]   = ed[(size_t)e*128 + 64 + lane];
  int as = an[s], at = an[t];
  xe[128+lane]  = st[as*64 + lane];
  xe[192+lane]  = tt[at*64 + lane];
  __syncthreads();
  float acc = b1[lane];
  for(int k=0;k<256;k++) acc += xe[k]*w1[k*64+lane];
  float mu = wsum64(acc)*(1.f/64.f);
  float d = acc - mu;
  float var = wsum64(d*d)*(1.f/64.f);
  float nrm = d*rsqrtf(var+1e-5f)*g1[lane]+bb1[lane];
  h1s[lane] = siluf(nrm);
  __syncthreads();
  float acc2 = b2[lane];
  for(int k=0;k<64;k++) acc2 += h1s[k]*w2[k*64+lane];
  mu = wsum64(acc2)*(1.f/64.f);
  d = acc2-mu;
  var = wsum64(d*d)*(1.f/64.f);
  nrm = d*rsqrtf(var+1e-5f)*g2[lane]+bb2[lane];
  h2out[(size_t)e*64+lane] = siluf(nrm);
}

// ---------------- generic fp32 GEMM: C = A@B (+bias), split column output ----------------
__global__ __launch_bounds__(256) void gemm_kernel(
    const float* __restrict__ A, int lda,
    const float* __restrict__ B, int ldb,
    const float* __restrict__ bias,
    float* __restrict__ C1, int ldc1, int split,
    float* __restrict__ C2, int ldc2,
    int M, int N, int K){
  __shared__ float As[8][128];
  __shared__ float Bs[8][128];
  int t = threadIdx.x;
  int n0 = blockIdx.x*128, m0 = blockIdx.y*128;
  int arow = t>>1, aseg = t&1;
  int grow = m0 + arow; if(grow >= M) grow = M-1;
  const float* Aptr = A + (size_t)grow*lda + aseg*4;
  int bk = t>>5, bc4 = t&31;
  const float* Bptr = B + (size_t)bk*ldb + n0 + bc4*4;
  int tx = t&15, ty = t>>4;
  float acc[8][8] = {};
  int nk = K/8;
  for(int kt=0; kt<nk; kt++){
    float4 av = *(const float4*)(Aptr + (size_t)kt*8);
    float4 bv = *(const float4*)(Bptr + (size_t)kt*8*ldb);
    As[aseg*4+0][arow]=av.x; As[aseg*4+1][arow]=av.y; As[aseg*4+2][arow]=av.z; As[aseg*4+3][arow]=av.w;
    *(float4*)&Bs[bk][bc4*4] = bv;
    __syncthreads();
#pragma unroll
    for(int k=0;k<8;k++){
      float4 a0 = *(const float4*)&As[k][ty*8];
      float4 a1 = *(const float4*)&As[k][ty*8+4];
      float4 b0 = *(const float4*)&Bs[k][tx*8];
      float4 b1 = *(const float4*)&Bs[k][tx*8+4];
      float ar[8] = {a0.x,a0.y,a0.z,a0.w,a1.x,a1.y,a1.z,a1.w};
      float br[8] = {b0.x,b0.y,b0.z,b0.w,b1.x,b1.y,b1.z,b1.w};
#pragma unroll
      for(int i=0;i<8;i++)
#pragma unroll
        for(int j=0;j<8;j++)
          acc[i][j] += ar[i]*br[j];
    }
    __syncthreads();
  }
#pragma unroll
  for(int i=0;i<8;i++){
    int row = m0 + ty*8 + i;
    if(row < M){
#pragma unroll
      for(int j=0;j<8;j++){
        int col = n0 + tx*8 + j;
        float v = acc[i][j];
        if(bias) v += bias[col];
        if(col < split) C1[(size_t)row*ldc1 + col] = v;
        else            C2[(size_t)row*ldc2 + (col-split)] = v;
      }
    }
  }
}

// ---------------- wigner apply + concat + PERM + rad scale -> msg1 (C,25,256) ----------------
__global__ __launch_bounds__(256) void wigner1_kernel(
    const float* __restrict__ x, const float* __restrict__ wigner,
    const int* __restrict__ src, const int* __restrict__ tgt,
    const float* __restrict__ rad, float* __restrict__ msg1){
  int e = blockIdx.x; int t = threadIdx.x;
  __shared__ float wig[625];
  __shared__ float4 cat4[1600]; // [l][c4] 25 x 64
  int s = src[e], tg = tgt[e];
  for(int i=t;i<625;i+=256) wig[i] = wigner[(size_t)e*625 + i];
  const float4* xs = (const float4*)(x + (size_t)s*3200);
  const float4* xt = (const float4*)(x + (size_t)tg*3200);
  for(int idx=t; idx<1600; idx+=256){
    int l = idx>>6, slot = idx&63;
    cat4[idx] = (slot<32) ? xs[l*32 + slot] : xt[l*32 + (slot-32)];
  }
  __syncthreads();
  int wave = t>>6, lane = t&63;
  for(int p=wave; p<25; p+=4){
    int pl = c_PERM[p];
    float4 acc = {0.f,0.f,0.f,0.f};
#pragma unroll
    for(int l=0;l<25;l++){
      float w = wig[pl*25 + l];
      float4 c = cat4[l*64 + lane];
      acc.x += w*c.x; acc.y += w*c.y; acc.z += w*c.z; acc.w += w*c.w;
    }
    float4 rd = *(const float4*)(rad + (size_t)e*3840 + c_ROFF[p] + lane*4);
    acc.x*=rd.x; acc.y*=rd.y; acc.z*=rd.z; acc.w*=rd.w;
    *((float4*)(msg1 + ((size_t)e*25+p)*256 + lane*4)) = acc;
  }
}

// ---------------- grid gating ----------------
__global__ __launch_bounds__(64) void grid_kernel(
    const float* __restrict__ msg2, const float* __restrict__ x0e,
    const float* __restrict__ tg, const float* __restrict__ fg,
    float* __restrict__ msg_m2){
  int e = blockIdx.x; int lane = threadIdx.x;
  float r[25];
#pragma unroll
  for(int i=0;i<25;i++) r[i] = msg2[((size_t)e*25 + INV_CE[i])*64 + lane];
  float s2[25];
#pragma unroll
  for(int i=0;i<25;i++) s2[i]=0.f;
  for(int g=0; g<100; g++){
    float tv=0.f;
#pragma unroll
    for(int i=0;i<25;i++) tv += tg[g*25+i]*r[i];
    tv = siluf(tv);
#pragma unroll
    for(int i=0;i<25;i++) s2[i] += fg[g*25+i]*tv;
  }
  float gate = siluf(x0e[(size_t)e*576 + 512 + lane]);
#pragma unroll
  for(int p=0;p<25;p++){
    int lp = PERM_CE[p];
    float v = (lp==0) ? gate : s2[lp];
    msg_m2[((size_t)e*25+p)*64 + lane] = v;
  }
}

// ---------------- alpha: LN + gate + logits -> ex=exp(logit), segsum atomics ----------------
// Softmax is shift-invariant; logits here are O(3) so exp() cannot overflow:
// scatter unnormalized ex-weighted values, divide by segsum in proj.
__global__ __launch_bounds__(64) void alpha_kernel(
    const float* __restrict__ x0e, const float* __restrict__ g, const float* __restrict__ b,
    const float* __restrict__ adot, const int* __restrict__ tgt,
    float* __restrict__ exb, float* __restrict__ ssum){
  int e = blockIdx.x; int lane = threadIdx.x;
  int t = tgt[e];
  float gg = g[lane], bb = b[lane];
  for(int h=0;h<8;h++){
    float v = x0e[(size_t)e*576 + h*64 + lane];
    float mu = wsum64(v)*(1.f/64.f);
    float d = v-mu;
    float var = wsum64(d*d)*(1.f/64.f);
    float a = d*rsqrtf(var+1e-5f)*gg+bb;
    float sig = 1.f/(1.f+expf(-a));
    float a2 = 0.6f*a + 0.4f*a*(2.f*sig-1.f);
    float p = a2*adot[h*64+lane];
    float lg = wsum64(p);
    if(lane==0){
      float ex = expf(lg);
      exb[e*8+h]=ex;
      atomicAdd(&ssum[t*8+h], ex);
    }
  }
}

// ---------------- wigner^T + ex scale + scatter-add into node (unnormalized) ----------------
__global__ __launch_bounds__(256) void wigner2_kernel(
    const float* __restrict__ wigner, const float* __restrict__ msg3,
    const float* __restrict__ exb, const int* __restrict__ tgt,
    float* __restrict__ node){
  int e = blockIdx.x; int t = threadIdx.x;
  __shared__ float wig2[625];   // [q (m-order)][l]
  __shared__ float4 m3[800];    // [q][c4] 25 x 32
  __shared__ float al[8];
  int tg = tgt[e];
  for(int i=t;i<625;i+=256){ int q=i/25, l=i%25; wig2[i] = wigner[((size_t)e*25 + c_PERM[q])*25 + l]; }
  const float4* m3g = (const float4*)(msg3 + (size_t)e*3200);
  for(int i=t;i<800;i+=256) m3[i] = m3g[i];
  if(t<8) al[t] = exb[e*8+t];
  __syncthreads();
  int slot = t&31; int grp = t>>5;
  float* nb = node + (size_t)tg*3200;
  for(int l=grp; l<25; l+=8){
    float4 acc={0.f,0.f,0.f,0.f};
#pragma unroll
    for(int q=0;q<25;q++){
      float w = wig2[q*25+l];
      float4 m = m3[q*32+slot];
      acc.x+=w*m.x; acc.y+=w*m.y; acc.z+=w*m.z; acc.w+=w*m.w;
    }
    float a = al[slot>>2];
    int c = slot*4;
    atomicAdd(nb + l*128 + c+0, acc.x*a);
    atomicAdd(nb + l*128 + c+1, acc.y*a);
    atomicAdd(nb + l*128 + c+2, acc.z*a);
    atomicAdd(nb + l*128 + c+3, acc.w*a);
  }
}

// ---------------- output projection (applies 1/segsum normalization) ----------------
__global__ __launch_bounds__(256) void proj_kernel(
    const float* __restrict__ node, const float* __restrict__ ssum,
    const float* __restrict__ pwt, const float* __restrict__ proj_b,
    float* __restrict__ out, int NN){
  int n0 = blockIdx.x*2; int t = threadIdx.x;
  __shared__ float nd[2][3200];
  __shared__ float inv[2][8];
  if(t<16){
    int j=t>>3, h=t&7;
    int n=n0+j; if(n>=NN) n=NN-1;
    inv[j][h] = 1.f/(ssum[n*8+h] + 1e-16f);
  }
  __syncthreads();
  int n1 = (n0+1 < NN) ? (n0+1) : (NN-1);
  for(int i=t;i<3200;i+=256){
    int h = (i&127)>>4;
    nd[0][i] = node[(size_t)n0*3200 + i] * inv[0][h];
    nd[1][i] = node[(size_t)n1*3200 + i] * inv[1][h];
  }
  __syncthreads();
  int o = t&127, half = t>>7;
  for(int p=half;p<25;p+=2){
    int l = c_EXPAND[p];
    const float* w = pwt + l*16384;  // [i][o]
    float a0=0.f, a1=0.f;
    for(int i=0;i<128;i++){
      float wv = w[i*128+o];
      a0 += nd[0][p*128+i]*wv;
      a1 += nd[1][p*128+i]*wv;
    }
    float bs = (p==0)? proj_b[o] : 0.f;
    out[((size_t)n0*25+p)*128 + o] = a0 + bs;
    if(n0+1 < NN) out[((size_t)(n0+1)*25+p)*128 + o] = a1 + bs;
  }
}

// ---------------- launcher ----------------
extern "C" void kernel_launch(void* const* d_in, const int* in_sizes, int n_in,
                              void* d_out, int out_size, void* d_ws, size_t ws_size,
                              hipStream_t stream) {
  const float* x           = (const float*)d_in[0];
  const float* edge_dist   = (const float*)d_in[1];
  const float* src_table   = (const float*)d_in[2];
  const float* tgt_table   = (const float*)d_in[3];
  const float* rad_w1      = (const float*)d_in[4];
  const float* rad_b1      = (const float*)d_in[5];
  const float* rad_ln1_g   = (const float*)d_in[6];
  const float* rad_ln1_b   = (const float*)d_in[7];
  const float* rad_w2      = (const float*)d_in[8];
  const float* rad_b2      = (const float*)d_in[9];
  const float* rad_ln2_g   = (const float*)d_in[10];
  const float* rad_ln2_b   = (const float*)d_in[11];
  const float* rad_w3      = (const float*)d_in[12];
  const float* rad_b3      = (const float*)d_in[13];
  const float* wigner      = (const float*)d_in[14];
  const float* c1_fc0_w    = (const float*)d_in[15];
  const float* c1_fc0_b    = (const float*)d_in[16];
  const float* c1_wm[4]    = {(const float*)d_in[17],(const float*)d_in[18],(const float*)d_in[19],(const float*)d_in[20]};
  const float* to_grid     = (const float*)d_in[21];
  const float* from_grid   = (const float*)d_in[22];
  const float* alpha_ln_g  = (const float*)d_in[23];
  const float* alpha_ln_b  = (const float*)d_in[24];
  const float* alpha_dot   = (const float*)d_in[25];
  const float* c2_fc0_w    = (const float*)d_in[26];
  const float* c2_fc0_b    = (const float*)d_in[27];
  const float* c2_wm[4]    = {(const float*)d_in[28],(const float*)d_in[29],(const float*)d_in[30],(const float*)d_in[31]};
  const float* proj_w      = (const float*)d_in[32];
  const float* proj_b      = (const float*)d_in[33];
  const int*   atomic_nums = (const int*)d_in[34];
  const int*   edge_index  = (const int*)d_in[35];
  float* out = (float*)d_out;
  (void)n_in; (void)out_size;

  const int E  = in_sizes[35]/2;   // 25000
  const int NN = in_sizes[34];     // 2500

  // --- choose chunk size from ws_size (constant across calls -> graph-safe) ---
  const size_t W1T_FL = 2*(1024*512 + 768*384 + 512*256 + 256*128); // 1,966,080
  const size_t W2T_FL = 2*(256*1024 + 192*768 + 128*512 + 64*256);  //   983,040
  const size_t PWT_FL = 5*128*128;                                  //    81,920
  const size_t persist = (size_t)NN*8 + (size_t)NN*3200 + W1T_FL + W2T_FL + PWT_FL + 1024;
  const size_t wfl = ws_size / sizeof(float);
  const int copts[8] = {25000, 12500, 6250, 3125, 1250, 625, 250, 125};
  int C = 125;
  for(int i=0;i<8;i++){
    size_t need = (size_t)copts[i]*(6400+3840+576+8) + persist;
    if(need <= wfl){ C = copts[i]; break; }
  }

  // --- workspace layout ---
  float* ws = (float*)d_ws;
  float* msg1   = ws;                       // C*6400; later: msg_m2 (C*1600) + msg3 (C*3200)
  float* msg_m2 = ws;
  float* msg3   = ws + (size_t)C*1600;
  float* rad  = ws + (size_t)C*6400;        // C*3840; later msg2 (C*1600)
  float* msg2 = rad;
  float* x0e = rad + (size_t)C*3840;        // C*576; h2 (C*64) overlaid
  float* h2  = x0e;
  float* exb = x0e + (size_t)C*576;         // C*8
  float* ssum = exb + (size_t)C*8;          // NN*8
  float* node = ssum + (size_t)NN*8;        // NN*3200
  float* w1t[4]; w1t[0] = node + (size_t)NN*3200;
  w1t[1] = w1t[0] + 2*1024*512;
  w1t[2] = w1t[1] + 2*768*384;
  w1t[3] = w1t[2] + 2*512*256;
  float* w2t[4]; w2t[0] = w1t[3] + 2*256*128;
  w2t[1] = w2t[0] + 2*256*1024;
  w2t[2] = w2t[1] + 2*192*768;
  w2t[3] = w2t[2] + 2*128*512;
  float* pwt = w2t[3] + 2*64*256;

  hipMemsetAsync(node, 0, (size_t)NN*3200*sizeof(float), stream);
  hipMemsetAsync(ssum, 0, (size_t)NN*8*sizeof(float), stream);

  // --- weight transforms (once) ---
  const int K1[4] = {1024, 768, 512, 256}, C1c[4] = {512, 384, 256, 128};
  for(int i=0;i<4;i++){
    int tot = 2*K1[i]*C1c[i];
    wtrans_kernel<<<(tot+255)/256, 256, 0, stream>>>(c1_wm[i], w1t[i], K1[i], C1c[i]);
  }
  const int K2[4] = {256, 192, 128, 64}, C2c[4] = {1024, 768, 512, 256};
  for(int i=0;i<4;i++){
    int tot = 2*K2[i]*C2c[i];
    wtrans_kernel<<<(tot+255)/256, 256, 0, stream>>>(c2_wm[i], w2t[i], K2[i], C2c[i]);
  }
  ptrans_kernel<<<320, 256, 0, stream>>>(proj_w, pwt);

  const int OFF1[4] = {5,13,19,23};
  int nch = (E + C - 1)/C;
  for(int ch=0; ch<nch; ch++){
    int e0 = ch*C;
    int ce = (E - e0 < C) ? (E - e0) : C;
    const int* srcp = edge_index + e0;
    const int* tgtp = edge_index + E + e0;
    const float* wigp = wigner + (size_t)e0*625;
    int mt = (ce+127)/128;

    radial_kernel<<<ce, 64, 0, stream>>>(edge_dist + (size_t)e0*128, src_table, tgt_table,
        rad_w1, rad_b1, rad_ln1_g, rad_ln1_b, rad_w2, rad_b2, rad_ln2_g, rad_ln2_b,
        atomic_nums, srcp, tgtp, h2);
    gemm_kernel<<<dim3(3840/128, mt), 256, 0, stream>>>(h2, 64, rad_w3, 3840, rad_b3,
        rad, 3840, 3840, nullptr, 0, ce, 3840, 64);

    wigner1_kernel<<<ce, 256, 0, stream>>>(x, wigp, srcp, tgtp, rad, msg1);

    // conv1: G0 (split -> x0e | msg2 rows 0..4) + 4 m-block GEMMs
    gemm_kernel<<<dim3(896/128, mt), 256, 0, stream>>>(msg1, 6400, c1_fc0_w, 896, c1_fc0_b,
        x0e, 576, 576, msg2, 1600, ce, 896, 1280);
    for(int i=0;i<4;i++){
      int N = C1c[i], K = 2*K1[i];
      gemm_kernel<<<dim3(N/128, mt), 256, 0, stream>>>(msg1 + OFF1[i]*256, 6400, w1t[i], N, nullptr,
          msg2 + OFF1[i]*64, 1600, N, nullptr, 0, ce, N, K);
    }

    grid_kernel<<<ce, 64, 0, stream>>>(msg2, x0e, to_grid, from_grid, msg_m2);
    alpha_kernel<<<ce, 64, 0, stream>>>(x0e, alpha_ln_g, alpha_ln_b, alpha_dot, tgtp, exb, ssum);

    // conv2
    gemm_kernel<<<dim3(640/128, mt), 256, 0, stream>>>(msg_m2, 1600, c2_fc0_w, 640, c2_fc0_b,
        msg3, 3200, 640, nullptr, 0, ce, 640, 320);
    for(int i=0;i<4;i++){
      int N = C2c[i], K = 2*K2[i];
      gemm_kernel<<<dim3(N/128, mt), 256, 0, stream>>>(msg_m2 + OFF1[i]*64, 1600, w2t[i], N, nullptr,
          msg3 + OFF1[i]*128, 3200, N, nullptr, 0, ce, N, K);
    }

    wigner2_kernel<<<ce, 256, 0, stream>>>(wigp, msg3, exb, tgtp, node);
  }

  proj_kernel<<<(NN+1)/2, 256, 0, stream>>>(node, ssum, pwt, proj_b, out, NN);
}

// Round 3
// 4070.705 us; speedup vs baseline: 3.2564x; 3.2564x over previous
//
#include <hip/hip_runtime.h>
#include <cstddef>

typedef unsigned short u16;
typedef __attribute__((ext_vector_type(8))) short short8;
typedef __attribute__((ext_vector_type(4))) float float4v;

// ---------------- constants ----------------
__constant__ int c_PERM[25] = {0,2,6,12,20, 1,5,11,19, 3,7,13,21, 4,10,18, 8,14,22, 9,17, 15,23, 16,24};
__constant__ int c_ROFF[25] = {0,256,512,768,1024, 1280,1536,1792,2048, 1280,1536,1792,2048,
                               2304,2560,2816, 2304,2560,2816, 3072,3328, 3072,3328, 3584,3584};
__constant__ int c_EXPAND[25] = {0,1,1,1,2,2,2,2,2,3,3,3,3,3,3,3,4,4,4,4,4,4,4,4,4};

static constexpr int PERM_CE[25] = {0,2,6,12,20, 1,5,11,19, 3,7,13,21, 4,10,18, 8,14,22, 9,17, 15,23, 16,24};
static constexpr int INV_CE[25]  = {0,5,1,9,13, 6,2,10,16,19, 14,7,3,11,17, 21,23,20,15,8, 4,12,18,22,24};

__device__ __forceinline__ float wsum64(float v){
#pragma unroll
  for(int m=32;m>0;m>>=1) v += __shfl_xor(v, m, 64);
  return v;
}
__device__ __forceinline__ float siluf(float x){ return x/(1.f+expf(-x)); }

// split fp32 -> bf16 hi + bf16 lo (RNE), raw bits
__device__ __forceinline__ void bsplit(float v, u16 &h, u16 &l){
  unsigned u = __float_as_uint(v);
  unsigned hb = (u + 0x7FFFu + ((u>>16)&1u)) >> 16;
  h = (u16)hb;
  float r = v - __uint_as_float(hb<<16);
  unsigned u2 = __float_as_uint(r);
  l = (u16)((u2 + 0x7FFFu + ((u2>>16)&1u)) >> 16);
}

// ---------------- weight transforms ----------------
// conv m weights: W(K,C2) -> logical W2(2K,C2) -> transposed split (C2,2K) h/l
__global__ __launch_bounds__(256) void wtrans_kernel(const float* __restrict__ W, u16* __restrict__ Wh, u16* __restrict__ Wl, int K, int C2){
  int idx = blockIdx.x*256 + threadIdx.x;
  int K2 = 2*K;
  if(idx >= C2*K2) return;
  int n = idx / K2, k2 = idx % K2;
  int half = C2>>1;
  float v;
  if(k2 < K) v = W[k2*C2 + n];
  else { int k = k2-K; v = (n<half) ? -W[k*C2 + half + n] : W[k*C2 + n - half]; }
  u16 h,l; bsplit(v,h,l);
  Wh[idx]=h; Wl[idx]=l;
}

// fc weights: W(K,N) -> transposed split (N,K) h/l
__global__ __launch_bounds__(256) void fctrans_kernel(const float* __restrict__ W, u16* __restrict__ Wh, u16* __restrict__ Wl, int K, int N){
  int idx = blockIdx.x*256 + threadIdx.x;
  if(idx >= N*K) return;
  int n = idx / K, k = idx % K;
  u16 h,l; bsplit(W[(size_t)k*N + n],h,l);
  Wh[idx]=h; Wl[idx]=l;
}

// proj_w (5,128o,128i) -> pwt (5,128i,128o) fp32
__global__ __launch_bounds__(256) void ptrans_kernel(const float* __restrict__ pw, float* __restrict__ pwt){
  int idx = blockIdx.x*256+threadIdx.x;
  if(idx >= 5*16384) return;
  int l = idx>>14, r = idx & 16383, i = r>>7, o = r&127;
  pwt[idx] = pw[(l<<14) + (o<<7) + i];
}

// ---------------- radial MLP -> h2 split bf16 ----------------
__global__ __launch_bounds__(64) void radial_kernel(
    const float* __restrict__ ed, const float* __restrict__ st, const float* __restrict__ tt,
    const float* __restrict__ w1, const float* __restrict__ b1, const float* __restrict__ g1, const float* __restrict__ bb1,
    const float* __restrict__ w2, const float* __restrict__ b2, const float* __restrict__ g2, const float* __restrict__ bb2,
    const int* __restrict__ an, const int* __restrict__ src, const int* __restrict__ tgt,
    u16* __restrict__ h2h, u16* __restrict__ h2l){
  int e = blockIdx.x; int lane = threadIdx.x;
  __shared__ float xe[256];
  __shared__ float h1s[64];
  int s = src[e], t = tgt[e];
  xe[lane]      = ed[(size_t)e*128 + lane];
  xe[64+lane]   = ed[(size_t)e*128 + 64 + lane];
  int as = an[s], at = an[t];
  xe[128+lane]  = st[as*64 + lane];
  xe[192+lane]  = tt[at*64 + lane];
  __syncthreads();
  float acc = b1[lane];
  for(int k=0;k<256;k++) acc += xe[k]*w1[k*64+lane];
  float mu = wsum64(acc)*(1.f/64.f);
  float d = acc - mu;
  float var = wsum64(d*d)*(1.f/64.f);
  float nrm = d*rsqrtf(var+1e-5f)*g1[lane]+bb1[lane];
  h1s[lane] = siluf(nrm);
  __syncthreads();
  float acc2 = b2[lane];
  for(int k=0;k<64;k++) acc2 += h1s[k]*w2[k*64+lane];
  mu = wsum64(acc2)*(1.f/64.f);
  d = acc2-mu;
  var = wsum64(d*d)*(1.f/64.f);
  nrm = d*rsqrtf(var+1e-5f)*g2[lane]+bb2[lane];
  u16 h,l; bsplit(siluf(nrm),h,l);
  h2h[(size_t)e*64+lane]=h; h2l[(size_t)e*64+lane]=l;
}

// ---------------- grouped split-bf16 MFMA GEMM ----------------
// C = A@B^T_stored (+bias). A: (M,K) rows stride lda, split h/l u16. B stored (N,K) h/l.
// block tile 128x128, 4 waves each 64x64 (4x4 of 16x16x32), K-step 32.
struct GrpArgs {
  const u16* Ah[6]; const u16* Al[6];
  const u16* Bh[6]; const u16* Bl[6];
  const float* bias[6]; float* C1[6]; float* C2[6];
  int lda[6]; int K[6]; int ldc1[6]; int ldc2[6]; int split[6];
  int xoff[7]; int ng; int M;
};

__global__ __launch_bounds__(256) void mgemm_kernel(GrpArgs a){
  __shared__ __align__(16) u16 Ash[128*40];
  __shared__ __align__(16) u16 Asl[128*40];
  __shared__ __align__(16) u16 Bsh[128*40];
  __shared__ __align__(16) u16 Bsl[128*40];
  int bx = blockIdx.x;
  int g = 0;
  while(g+1 < a.ng && bx >= a.xoff[g+1]) g++;
  int nx = bx - a.xoff[g];
  int n0 = nx*128, m0 = blockIdx.y*128;
  const int M = a.M, K = a.K[g], lda = a.lda[g];
  const u16* __restrict__ Ah = a.Ah[g]; const u16* __restrict__ Al = a.Al[g];
  const u16* __restrict__ Bh = a.Bh[g]; const u16* __restrict__ Bl = a.Bl[g];
  int t = threadIdx.x;
  int r0 = t>>2, k80 = (t&3)*8;
  int r1 = r0 + 64;
  int ar0 = m0 + r0; if(ar0 >= M) ar0 = M-1;
  int ar1 = m0 + r1; if(ar1 >= M) ar1 = M-1;
  const u16* Ap0h = Ah + (size_t)ar0*lda + k80;
  const u16* Ap1h = Ah + (size_t)ar1*lda + k80;
  const u16* Ap0l = Al + (size_t)ar0*lda + k80;
  const u16* Ap1l = Al + (size_t)ar1*lda + k80;
  const u16* Bp0h = Bh + (size_t)(n0+r0)*K + k80;
  const u16* Bp1h = Bh + (size_t)(n0+r1)*K + k80;
  const u16* Bp0l = Bl + (size_t)(n0+r0)*K + k80;
  const u16* Bp1l = Bl + (size_t)(n0+r1)*K + k80;
  int sA = r0*40 + k80;
  int sB = r1*40 + k80;

  int wave = t>>6, lane = t&63;
  int wr = wave>>1, wc = wave&1;
  int ml = lane&15, q = lane>>4;
  int aoff = (wr*64 + ml)*40 + q*8;
  int boff = (wc*64 + ml)*40 + q*8;

  float4v acc[4][4];
#pragma unroll
  for(int i=0;i<4;i++)
#pragma unroll
    for(int j=0;j<4;j++) acc[i][j] = 0.f;

  for(int k0=0; k0<K; k0+=32){
    short8 va0 = *(const short8*)(Ap0h + k0);
    short8 va1 = *(const short8*)(Ap1h + k0);
    short8 va2 = *(const short8*)(Ap0l + k0);
    short8 va3 = *(const short8*)(Ap1l + k0);
    short8 vb0 = *(const short8*)(Bp0h + k0);
    short8 vb1 = *(const short8*)(Bp1h + k0);
    short8 vb2 = *(const short8*)(Bp0l + k0);
    short8 vb3 = *(const short8*)(Bp1l + k0);
    __syncthreads();
    *(short8*)(Ash + sA) = va0;
    *(short8*)(Ash + sB) = va1;
    *(short8*)(Asl + sA) = va2;
    *(short8*)(Asl + sB) = va3;
    *(short8*)(Bsh + sA) = vb0;
    *(short8*)(Bsh + sB) = vb1;
    *(short8*)(Bsl + sA) = vb2;
    *(short8*)(Bsl + sB) = vb3;
    __syncthreads();
    short8 afh[4], afl[4], bfh[4], bfl[4];
#pragma unroll
    for(int i=0;i<4;i++){
      afh[i] = *(const short8*)(Ash + aoff + i*640);
      afl[i] = *(const short8*)(Asl + aoff + i*640);
      bfh[i] = *(const short8*)(Bsh + boff + i*640);
      bfl[i] = *(const short8*)(Bsl + boff + i*640);
    }
#pragma unroll
    for(int i=0;i<4;i++)
#pragma unroll
      for(int j=0;j<4;j++){
        acc[i][j] = __builtin_amdgcn_mfma_f32_16x16x32_bf16(afh[i], bfh[j], acc[i][j], 0,0,0);
        acc[i][j] = __builtin_amdgcn_mfma_f32_16x16x32_bf16(afh[i], bfl[j], acc[i][j], 0,0,0);
        acc[i][j] = __builtin_amdgcn_mfma_f32_16x16x32_bf16(afl[i], bfh[j], acc[i][j], 0,0,0);
      }
  }
  const float* bias = a.bias[g];
  int split = a.split[g];
  float* C1 = a.C1[g]; float* C2 = a.C2[g];
  int ldc1 = a.ldc1[g], ldc2 = a.ldc2[g];
#pragma unroll
  for(int i=0;i<4;i++){
    int rowb = m0 + wr*64 + i*16 + q*4;
#pragma unroll
    for(int r=0;r<4;r++){
      int row = rowb + r;
      if(row < M){
#pragma unroll
        for(int j=0;j<4;j++){
          int col = n0 + wc*64 + j*16 + ml;
          float v = acc[i][j][r];
          if(bias) v += bias[col];
          if(col < split) C1[(size_t)row*ldc1 + col] = v;
          else            C2[(size_t)row*ldc2 + (col-split)] = v;
        }
      }
    }
  }
}

// ---------------- wigner apply + concat + PERM + rad scale -> msg1 split bf16 ----------------
__global__ __launch_bounds__(256) void wigner1_kernel(
    const float* __restrict__ x, const float* __restrict__ wigner,
    const int* __restrict__ src, const int* __restrict__ tgt,
    const float* __restrict__ rad, u16* __restrict__ msg1h, u16* __restrict__ msg1l){
  int e = blockIdx.x; int t = threadIdx.x;
  __shared__ float wig[625];
  __shared__ float4 cat4[1600]; // [l][c4] 25 x 64
  int s = src[e], tg = tgt[e];
  for(int i=t;i<625;i+=256) wig[i] = wigner[(size_t)e*625 + i];
  const float4* xs = (const float4*)(x + (size_t)s*3200);
  const float4* xt = (const float4*)(x + (size_t)tg*3200);
  for(int idx=t; idx<1600; idx+=256){
    int l = idx>>6, slot = idx&63;
    cat4[idx] = (slot<32) ? xs[l*32 + slot] : xt[l*32 + (slot-32)];
  }
  __syncthreads();
  int wave = t>>6, lane = t&63;
  for(int p=wave; p<25; p+=4){
    int pl = c_PERM[p];
    float4 acc = {0.f,0.f,0.f,0.f};
#pragma unroll
    for(int l=0;l<25;l++){
      float w = wig[pl*25 + l];
      float4 c = cat4[l*64 + lane];
      acc.x += w*c.x; acc.y += w*c.y; acc.z += w*c.z; acc.w += w*c.w;
    }
    float4 rd = *(const float4*)(rad + (size_t)e*3840 + c_ROFF[p] + lane*4);
    acc.x*=rd.x; acc.y*=rd.y; acc.z*=rd.z; acc.w*=rd.w;
    u16 h0,h1,h2,h3,l0,l1,l2,l3;
    bsplit(acc.x,h0,l0); bsplit(acc.y,h1,l1); bsplit(acc.z,h2,l2); bsplit(acc.w,h3,l3);
    size_t base = (size_t)e*6400 + p*256 + lane*4;
    *(uint2*)(msg1h + base) = make_uint2((unsigned)h0 | ((unsigned)h1<<16), (unsigned)h2 | ((unsigned)h3<<16));
    *(uint2*)(msg1l + base) = make_uint2((unsigned)l0 | ((unsigned)l1<<16), (unsigned)l2 | ((unsigned)l3<<16));
  }
}

// ---------------- grid gating -> msg_m2 split bf16 ----------------
__global__ __launch_bounds__(64) void grid_kernel(
    const float* __restrict__ msg2, const float* __restrict__ x0e,
    const float* __restrict__ tg, const float* __restrict__ fg,
    u16* __restrict__ m2h, u16* __restrict__ m2l){
  int e = blockIdx.x; int lane = threadIdx.x;
  float r[25];
#pragma unroll
  for(int i=0;i<25;i++) r[i] = msg2[((size_t)e*25 + INV_CE[i])*64 + lane];
  float s2[25];
#pragma unroll
  for(int i=0;i<25;i++) s2[i]=0.f;
  for(int g=0; g<100; g++){
    float tv=0.f;
#pragma unroll
    for(int i=0;i<25;i++) tv += tg[g*25+i]*r[i];
    tv = siluf(tv);
#pragma unroll
    for(int i=0;i<25;i++) s2[i] += fg[g*25+i]*tv;
  }
  float gate = siluf(x0e[(size_t)e*576 + 512 + lane]);
#pragma unroll
  for(int p=0;p<25;p++){
    int lp = PERM_CE[p];
    float v = (lp==0) ? gate : s2[lp];
    u16 h,l; bsplit(v,h,l);
    size_t idx = ((size_t)e*25+p)*64 + lane;
    m2h[idx]=h; m2l[idx]=l;
  }
}

// ---------------- alpha: LN + gate + logits -> ex=exp(logit), segsum atomics ----------------
__global__ __launch_bounds__(64) void alpha_kernel(
    const float* __restrict__ x0e, const float* __restrict__ g, const float* __restrict__ b,
    const float* __restrict__ adot, const int* __restrict__ tgt,
    float* __restrict__ exb, float* __restrict__ ssum){
  int e = blockIdx.x; int lane = threadIdx.x;
  int t = tgt[e];
  float gg = g[lane], bb = b[lane];
  for(int h=0;h<8;h++){
    float v = x0e[(size_t)e*576 + h*64 + lane];
    float mu = wsum64(v)*(1.f/64.f);
    float d = v-mu;
    float var = wsum64(d*d)*(1.f/64.f);
    float a = d*rsqrtf(var+1e-5f)*gg+bb;
    float sig = 1.f/(1.f+expf(-a));
    float a2 = 0.6f*a + 0.4f*a*(2.f*sig-1.f);
    float p = a2*adot[h*64+lane];
    float lg = wsum64(p);
    if(lane==0){
      float ex = expf(lg);
      exb[e*8+h]=ex;
      atomicAdd(&ssum[t*8+h], ex);
    }
  }
}

// ---------------- wigner^T + ex scale + scatter-add into node ----------------
__global__ __launch_bounds__(256) void wigner2_kernel(
    const float* __restrict__ wigner, const float* __restrict__ msg3,
    const float* __restrict__ exb, const int* __restrict__ tgt,
    float* __restrict__ node){
  int e = blockIdx.x; int t = threadIdx.x;
  __shared__ float wig2[625];   // [q (m-order)][l]
  __shared__ float4 m3[800];    // [q][c4] 25 x 32
  __shared__ float al[8];
  int tg = tgt[e];
  for(int i=t;i<625;i+=256){ int q=i/25, l=i%25; wig2[i] = wigner[((size_t)e*25 + c_PERM[q])*25 + l]; }
  const float4* m3g = (const float4*)(msg3 + (size_t)e*3200);
  for(int i=t;i<800;i+=256) m3[i] = m3g[i];
  if(t<8) al[t] = exb[e*8+t];
  __syncthreads();
  int slot = t&31; int grp = t>>5;
  float* nb = node + (size_t)tg*3200;
  for(int l=grp; l<25; l+=8){
    float4 acc={0.f,0.f,0.f,0.f};
#pragma unroll
    for(int q=0;q<25;q++){
      float w = wig2[q*25+l];
      float4 m = m3[q*32+slot];
      acc.x+=w*m.x; acc.y+=w*m.y; acc.z+=w*m.z; acc.w+=w*m.w;
    }
    float a = al[slot>>2];
    int c = slot*4;
    atomicAdd(nb + l*128 + c+0, acc.x*a);
    atomicAdd(nb + l*128 + c+1, acc.y*a);
    atomicAdd(nb + l*128 + c+2, acc.z*a);
    atomicAdd(nb + l*128 + c+3, acc.w*a);
  }
}

// ---------------- output projection (applies 1/segsum) ----------------
__global__ __launch_bounds__(256) void proj_kernel(
    const float* __restrict__ node, const float* __restrict__ ssum,
    const float* __restrict__ pwt, const float* __restrict__ proj_b,
    float* __restrict__ out, int NN){
  int n0 = blockIdx.x*2; int t = threadIdx.x;
  __shared__ float nd[2][3200];
  __shared__ float inv[2][8];
  if(t<16){
    int j=t>>3, h=t&7;
    int n=n0+j; if(n>=NN) n=NN-1;
    inv[j][h] = 1.f/(ssum[n*8+h] + 1e-16f);
  }
  __syncthreads();
  int n1 = (n0+1 < NN) ? (n0+1) : (NN-1);
  for(int i=t;i<3200;i+=256){
    int h = (i&127)>>4;
    nd[0][i] = node[(size_t)n0*3200 + i] * inv[0][h];
    nd[1][i] = node[(size_t)n1*3200 + i] * inv[1][h];
  }
  __syncthreads();
  int o = t&127, half = t>>7;
  for(int p=half;p<25;p+=2){
    int l = c_EXPAND[p];
    const float* w = pwt + l*16384;  // [i][o]
    float a0=0.f, a1=0.f;
    for(int i=0;i<128;i++){
      float wv = w[i*128+o];
      a0 += nd[0][p*128+i]*wv;
      a1 += nd[1][p*128+i]*wv;
    }
    float bs = (p==0)? proj_b[o] : 0.f;
    out[((size_t)n0*25+p)*128 + o] = a0 + bs;
    if(n0+1 < NN) out[((size_t)(n0+1)*25+p)*128 + o] = a1 + bs;
  }
}

// ---------------- launcher ----------------
extern "C" void kernel_launch(void* const* d_in, const int* in_sizes, int n_in,
                              void* d_out, int out_size, void* d_ws, size_t ws_size,
                              hipStream_t stream) {
  const float* x           = (const float*)d_in[0];
  const float* edge_dist   = (const float*)d_in[1];
  const float* src_table   = (const float*)d_in[2];
  const float* tgt_table   = (const float*)d_in[3];
  const float* rad_w1      = (const float*)d_in[4];
  const float* rad_b1      = (const float*)d_in[5];
  const float* rad_ln1_g   = (const float*)d_in[6];
  const float* rad_ln1_b   = (const float*)d_in[7];
  const float* rad_w2      = (const float*)d_in[8];
  const float* rad_b2      = (const float*)d_in[9];
  const float* rad_ln2_g   = (const float*)d_in[10];
  const float* rad_ln2_b   = (const float*)d_in[11];
  const float* rad_w3      = (const float*)d_in[12];
  const float* rad_b3      = (const float*)d_in[13];
  const float* wigner      = (const float*)d_in[14];
  const float* c1_fc0_w    = (const float*)d_in[15];
  const float* c1_fc0_b    = (const float*)d_in[16];
  const float* c1_wm[4]    = {(const float*)d_in[17],(const float*)d_in[18],(const float*)d_in[19],(const float*)d_in[20]};
  const float* to_grid     = (const float*)d_in[21];
  const float* from_grid   = (const float*)d_in[22];
  const float* alpha_ln_g  = (const float*)d_in[23];
  const float* alpha_ln_b  = (const float*)d_in[24];
  const float* alpha_dot   = (const float*)d_in[25];
  const float* c2_fc0_w    = (const float*)d_in[26];
  const float* c2_fc0_b    = (const float*)d_in[27];
  const float* c2_wm[4]    = {(const float*)d_in[28],(const float*)d_in[29],(const float*)d_in[30],(const float*)d_in[31]};
  const float* proj_w      = (const float*)d_in[32];
  const float* proj_b      = (const float*)d_in[33];
  const int*   atomic_nums = (const int*)d_in[34];
  const int*   edge_index  = (const int*)d_in[35];
  float* out = (float*)d_out;
  (void)n_in; (void)out_size;

  const int E  = in_sizes[35]/2;   // 25000
  const int NN = in_sizes[34];     // 2500

  // weight split sizes (u16 elements per buffer)
  const int K1[4] = {1024, 768, 512, 256}, C1c[4] = {512, 384, 256, 128};
  const int K2[4] = {256, 192, 128, 64},  C2c[4] = {1024, 768, 512, 256};
  const size_t W3T = 3840*64;           // 245760
  const size_t FC1 = 896*1280;          // 1146880
  const size_t W1S[4] = {512*2048, 384*1536, 256*1024, 128*512};
  const size_t FC2 = 640*320;           // 204800
  const size_t W2S[4] = {1024*512, 768*384, 512*256, 256*128};
  size_t wush = 2*(W3T + FC1 + W1S[0]+W1S[1]+W1S[2]+W1S[3] + FC2 + W2S[0]+W2S[1]+W2S[2]+W2S[3]);
  const size_t persist = (size_t)NN*8 + (size_t)NN*3200 + wush/2 + 81920 + 4096;
  const size_t wfl = ws_size / sizeof(float);
  const int copts[10] = {25000, 12500, 6250, 5000, 3125, 2500, 1250, 625, 250, 125};
  int C = 125;
  for(int i=0;i<10;i++){
    size_t need = (size_t)copts[i]*(6400+3840+576+8) + persist;
    if(need <= wfl){ C = copts[i]; break; }
  }

  // --- workspace layout ---
  float* ws = (float*)d_ws;
  u16* msg1h = (u16*)ws;                          // C*6400 u16
  u16* msg1l = msg1h + (size_t)C*6400;            // C*6400 u16  (ends at float C*6400)
  u16* m2h   = (u16*)ws;                          // reuse: C*1600 u16
  u16* m2l   = m2h + (size_t)C*1600;
  float* msg3 = ws + (size_t)C*1600;              // C*3200 fl
  float* rad  = ws + (size_t)C*6400;              // C*3840 fl; later msg2
  float* msg2 = rad;
  float* x0e  = rad + (size_t)C*3840;             // C*576 fl; h2 split overlaid
  u16* h2h = (u16*)x0e;
  u16* h2l = h2h + (size_t)C*64;
  float* exb  = x0e + (size_t)C*576;              // C*8
  float* ssum = exb + (size_t)C*8;                // NN*8
  float* node = ssum + (size_t)NN*8;              // NN*3200
  u16* wb = (u16*)(node + (size_t)NN*3200);
  u16 *w3h = wb, *w3l = w3h + W3T;
  u16 *f1h = w3l + W3T, *f1l = f1h + FC1;
  u16 *w1h[4], *w1l[4];
  u16* p = f1l + FC1;
  for(int i=0;i<4;i++){ w1h[i]=p; w1l[i]=p+W1S[i]; p += 2*W1S[i]; }
  u16 *f2h = p, *f2l = f2h + FC2; p = f2l + FC2;
  u16 *w2h[4], *w2l[4];
  for(int i=0;i<4;i++){ w2h[i]=p; w2l[i]=p+W2S[i]; p += 2*W2S[i]; }
  float* pwt = (float*)p;

  hipMemsetAsync(node, 0, (size_t)NN*3200*sizeof(float), stream);
  hipMemsetAsync(ssum, 0, (size_t)NN*8*sizeof(float), stream);

  // --- weight transforms ---
  fctrans_kernel<<<((int)W3T+255)/256, 256, 0, stream>>>(rad_w3, w3h, w3l, 64, 3840);
  fctrans_kernel<<<((int)FC1+255)/256, 256, 0, stream>>>(c1_fc0_w, f1h, f1l, 1280, 896);
  fctrans_kernel<<<((int)FC2+255)/256, 256, 0, stream>>>(c2_fc0_w, f2h, f2l, 320, 640);
  for(int i=0;i<4;i++)
    wtrans_kernel<<<((int)W1S[i]*2+255)/256, 256, 0, stream>>>(c1_wm[i], w1h[i], w1l[i], K1[i], C1c[i]);
  for(int i=0;i<4;i++)
    wtrans_kernel<<<((int)W2S[i]*2+255)/256, 256, 0, stream>>>(c2_wm[i], w2h[i], w2l[i], K2[i], C2c[i]);
  ptrans_kernel<<<320, 256, 0, stream>>>(proj_w, pwt);

  const int OFF1[4] = {5,13,19,23};
  int nch = (E + C - 1)/C;
  for(int ch=0; ch<nch; ch++){
    int e0 = ch*C;
    int ce = (E - e0 < C) ? (E - e0) : C;
    const int* srcp = edge_index + e0;
    const int* tgtp = edge_index + E + e0;
    const float* wigp = wigner + (size_t)e0*625;
    int mt = (ce+127)/128;

    radial_kernel<<<ce, 64, 0, stream>>>(edge_dist + (size_t)e0*128, src_table, tgt_table,
        rad_w1, rad_b1, rad_ln1_g, rad_ln1_b, rad_w2, rad_b2, rad_ln2_g, rad_ln2_b,
        atomic_nums, srcp, tgtp, h2h, h2l);

    // rad GEMM: (ce,64) @ (64,3840)
    {
      GrpArgs ga = {};
      ga.ng = 1; ga.M = ce;
      ga.Ah[0]=h2h; ga.Al[0]=h2l; ga.Bh[0]=w3h; ga.Bl[0]=w3l;
      ga.bias[0]=rad_b3; ga.C1[0]=rad; ga.C2[0]=nullptr;
      ga.lda[0]=64; ga.K[0]=64; ga.ldc1[0]=3840; ga.ldc2[0]=0; ga.split[0]=3840;
      ga.xoff[0]=0; ga.xoff[1]=30;
      mgemm_kernel<<<dim3(30, mt), 256, 0, stream>>>(ga);
    }

    wigner1_kernel<<<ce, 256, 0, stream>>>(x, wigp, srcp, tgtp, rad, msg1h, msg1l);

    // conv1 grouped: fc0 + 4 m-blocks
    {
      GrpArgs ga = {};
      ga.ng = 5; ga.M = ce;
      ga.Ah[0]=msg1h; ga.Al[0]=msg1l; ga.Bh[0]=f1h; ga.Bl[0]=f1l;
      ga.bias[0]=c1_fc0_b; ga.C1[0]=x0e; ga.C2[0]=msg2;
      ga.lda[0]=6400; ga.K[0]=1280; ga.ldc1[0]=576; ga.ldc2[0]=1600; ga.split[0]=576;
      int xo = 7;
      ga.xoff[0]=0; ga.xoff[1]=7;
      for(int i=0;i<4;i++){
        int gidx = i+1;
        ga.Ah[gidx]=msg1h + (size_t)OFF1[i]*256; ga.Al[gidx]=msg1l + (size_t)OFF1[i]*256;
        ga.Bh[gidx]=w1h[i]; ga.Bl[gidx]=w1l[i];
        ga.bias[gidx]=nullptr; ga.C1[gidx]=msg2 + OFF1[i]*64; ga.C2[gidx]=nullptr;
        ga.lda[gidx]=6400; ga.K[gidx]=2*K1[i]; ga.ldc1[gidx]=1600; ga.ldc2[gidx]=0; ga.split[gidx]=C1c[i];
        xo += C1c[i]/128;
        ga.xoff[gidx+1]=xo;
      }
      mgemm_kernel<<<dim3(xo, mt), 256, 0, stream>>>(ga);
    }

    grid_kernel<<<ce, 64, 0, stream>>>(msg2, x0e, to_grid, from_grid, m2h, m2l);
    alpha_kernel<<<ce, 64, 0, stream>>>(x0e, alpha_ln_g, alpha_ln_b, alpha_dot, tgtp, exb, ssum);

    // conv2 grouped: fc0 + 4 m-blocks
    {
      GrpArgs ga = {};
      ga.ng = 5; ga.M = ce;
      ga.Ah[0]=m2h; ga.Al[0]=m2l; ga.Bh[0]=f2h; ga.Bl[0]=f2l;
      ga.bias[0]=c2_fc0_b; ga.C1[0]=msg3; ga.C2[0]=nullptr;
      ga.lda[0]=1600; ga.K[0]=320; ga.ldc1[0]=3200; ga.ldc2[0]=0; ga.split[0]=640;
      int xo = 5;
      ga.xoff[0]=0; ga.xoff[1]=5;
      for(int i=0;i<4;i++){
        int gidx = i+1;
        ga.Ah[gidx]=m2h + (size_t)OFF1[i]*64; ga.Al[gidx]=m2l + (size_t)OFF1[i]*64;
        ga.Bh[gidx]=w2h[i]; ga.Bl[gidx]=w2l[i];
        ga.bias[gidx]=nullptr; ga.C1[gidx]=msg3 + OFF1[i]*128; ga.C2[gidx]=nullptr;
        ga.lda[gidx]=1600; ga.K[gidx]=2*K2[i]; ga.ldc1[gidx]=3200; ga.ldc2[gidx]=0; ga.split[gidx]=C2c[i];
        xo += C2c[i]/128;
        ga.xoff[gidx+1]=xo;
      }
      mgemm_kernel<<<dim3(xo, mt), 256, 0, stream>>>(ga);
    }

    wigner2_kernel<<<ce, 256, 0, stream>>>(wigp, msg3, exb, tgtp, node);
  }

  proj_kernel<<<(NN+1)/2, 256, 0, stream>>>(node, ssum, pwt, proj_b, out, NN);
}

// Round 4
// 3661.372 us; speedup vs baseline: 3.6204x; 1.1118x over previous
//
#include <hip/hip_runtime.h>
#include <cstddef>

typedef unsigned short u16;
typedef __attribute__((ext_vector_type(8))) short short8;
typedef __attribute__((ext_vector_type(4))) float float4v;

// ---------------- constants ----------------
__constant__ int c_PERM[25] = {0,2,6,12,20, 1,5,11,19, 3,7,13,21, 4,10,18, 8,14,22, 9,17, 15,23, 16,24};
__constant__ int c_ROFF[25] = {0,256,512,768,1024, 1280,1536,1792,2048, 1280,1536,1792,2048,
                               2304,2560,2816, 2304,2560,2816, 3072,3328, 3072,3328, 3584,3584};
__constant__ int c_EXPAND[25] = {0,1,1,1,2,2,2,2,2,3,3,3,3,3,3,3,4,4,4,4,4,4,4,4,4};

static constexpr int PERM_CE[25] = {0,2,6,12,20, 1,5,11,19, 3,7,13,21, 4,10,18, 8,14,22, 9,17, 15,23, 16,24};
static constexpr int INV_CE[25]  = {0,5,1,9,13, 6,2,10,16,19, 14,7,3,11,17, 21,23,20,15,8, 4,12,18,22,24};

__device__ __forceinline__ float wsum64(float v){
#pragma unroll
  for(int m=32;m>0;m>>=1) v += __shfl_xor(v, m, 64);
  return v;
}
__device__ __forceinline__ float siluf(float x){ return x/(1.f+expf(-x)); }

// split fp32 -> bf16 hi + bf16 lo (RNE), raw bits
__device__ __forceinline__ void bsplit(float v, u16 &h, u16 &l){
  unsigned u = __float_as_uint(v);
  unsigned hb = (u + 0x7FFFu + ((u>>16)&1u)) >> 16;
  h = (u16)hb;
  float r = v - __uint_as_float(hb<<16);
  unsigned u2 = __float_as_uint(r);
  l = (u16)((u2 + 0x7FFFu + ((u2>>16)&1u)) >> 16);
}

// ---------------- weight transforms ----------------
__global__ __launch_bounds__(256) void wtrans_kernel(const float* __restrict__ W, u16* __restrict__ Wh, u16* __restrict__ Wl, int K, int C2){
  int idx = blockIdx.x*256 + threadIdx.x;
  int K2 = 2*K;
  if(idx >= C2*K2) return;
  int n = idx / K2, k2 = idx % K2;
  int half = C2>>1;
  float v;
  if(k2 < K) v = W[k2*C2 + n];
  else { int k = k2-K; v = (n<half) ? -W[k*C2 + half + n] : W[k*C2 + n - half]; }
  u16 h,l; bsplit(v,h,l);
  Wh[idx]=h; Wl[idx]=l;
}

__global__ __launch_bounds__(256) void fctrans_kernel(const float* __restrict__ W, u16* __restrict__ Wh, u16* __restrict__ Wl, int K, int N){
  int idx = blockIdx.x*256 + threadIdx.x;
  if(idx >= N*K) return;
  int n = idx / K, k = idx % K;
  u16 h,l; bsplit(W[(size_t)k*N + n],h,l);
  Wh[idx]=h; Wl[idx]=l;
}

__global__ __launch_bounds__(256) void ptrans_kernel(const float* __restrict__ pw, float* __restrict__ pwt){
  int idx = blockIdx.x*256+threadIdx.x;
  if(idx >= 5*16384) return;
  int l = idx>>14, r = idx & 16383, i = r>>7, o = r&127;
  pwt[idx] = pw[(l<<14) + (o<<7) + i];
}

// ---------------- edge sort by target (per chunk) ----------------
__global__ __launch_bounds__(256) void hist_kernel(const int* __restrict__ tgt_all, int* __restrict__ cnt, int E, int C, int NN){
  int idx = blockIdx.x*256+threadIdx.x;
  if(idx>=E) return;
  atomicAdd(&cnt[(idx/C)*NN + tgt_all[idx]], 1);
}
__global__ __launch_bounds__(256) void scan_kernel(const int* __restrict__ cnt, int* __restrict__ basearr, int* __restrict__ cur, int NN, int C){
  int ch = blockIdx.x;
  __shared__ int sh[256];
  __shared__ int carry;
  if(threadIdx.x==0) carry = ch*C;
  __syncthreads();
  for(int t0=0; t0<NN; t0+=256){
    int i = t0 + threadIdx.x;
    int v = (i<NN)? cnt[ch*NN+i] : 0;
    sh[threadIdx.x]=v; __syncthreads();
    for(int off=1; off<256; off<<=1){
      int add = (threadIdx.x>=off)? sh[threadIdx.x-off]:0; __syncthreads();
      sh[threadIdx.x]+=add; __syncthreads();
    }
    int excl = carry + sh[threadIdx.x]-v;
    if(i<NN){ basearr[ch*NN+i]=excl; cur[ch*NN+i]=excl; }
    __syncthreads();
    if(threadIdx.x==255) carry += sh[255];
    __syncthreads();
  }
}
__global__ __launch_bounds__(256) void scatter_kernel(const int* __restrict__ tgt_all, int* __restrict__ cur, int* __restrict__ order, int E, int C, int NN){
  int idx = blockIdx.x*256+threadIdx.x;
  if(idx>=E) return;
  int ch = idx / C;
  int pos = atomicAdd(&cur[ch*NN + tgt_all[idx]], 1);
  order[pos] = idx;
}

// ---------------- radial MLP -> h2 split bf16 ----------------
__global__ __launch_bounds__(64) void radial_kernel(
    const float* __restrict__ ed, const float* __restrict__ st, const float* __restrict__ tt,
    const float* __restrict__ w1, const float* __restrict__ b1, const float* __restrict__ g1, const float* __restrict__ bb1,
    const float* __restrict__ w2, const float* __restrict__ b2, const float* __restrict__ g2, const float* __restrict__ bb2,
    const int* __restrict__ an, const int* __restrict__ src, const int* __restrict__ tgt,
    u16* __restrict__ h2h, u16* __restrict__ h2l){
  int e = blockIdx.x; int lane = threadIdx.x;
  __shared__ float xe[256];
  __shared__ float h1s[64];
  int s = src[e], t = tgt[e];
  xe[lane]      = ed[(size_t)e*128 + lane];
  xe[64+lane]   = ed[(size_t)e*128 + 64 + lane];
  int as = an[s], at = an[t];
  xe[128+lane]  = st[as*64 + lane];
  xe[192+lane]  = tt[at*64 + lane];
  __syncthreads();
  float acc = b1[lane];
  for(int k=0;k<256;k++) acc += xe[k]*w1[k*64+lane];
  float mu = wsum64(acc)*(1.f/64.f);
  float d = acc - mu;
  float var = wsum64(d*d)*(1.f/64.f);
  float nrm = d*rsqrtf(var+1e-5f)*g1[lane]+bb1[lane];
  h1s[lane] = siluf(nrm);
  __syncthreads();
  float acc2 = b2[lane];
  for(int k=0;k<64;k++) acc2 += h1s[k]*w2[k*64+lane];
  mu = wsum64(acc2)*(1.f/64.f);
  d = acc2-mu;
  var = wsum64(d*d)*(1.f/64.f);
  nrm = d*rsqrtf(var+1e-5f)*g2[lane]+bb2[lane];
  u16 h,l; bsplit(siluf(nrm),h,l);
  h2h[(size_t)e*64+lane]=h; h2l[(size_t)e*64+lane]=l;
}

// ---------------- grouped split-bf16 MFMA GEMM (prefetch-pipelined) ----------------
struct GrpArgs {
  const u16* Ah[6]; const u16* Al[6];
  const u16* Bh[6]; const u16* Bl[6];
  const float* bias[6]; float* C1[6]; float* C2[6];
  int lda[6]; int K[6]; int ldc1[6]; int ldc2[6]; int split[6];
  int xoff[7]; int ng; int M;
};

__global__ __launch_bounds__(256) void mgemm_kernel(GrpArgs a){
  __shared__ __align__(16) u16 Ash[128*40];
  __shared__ __align__(16) u16 Asl[128*40];
  __shared__ __align__(16) u16 Bsh[128*40];
  __shared__ __align__(16) u16 Bsl[128*40];
  int bx = blockIdx.x;
  int g = 0;
  while(g+1 < a.ng && bx >= a.xoff[g+1]) g++;
  int nx = bx - a.xoff[g];
  int n0 = nx*128, m0 = blockIdx.y*128;
  const int M = a.M, K = a.K[g], lda = a.lda[g];
  const u16* __restrict__ Ah = a.Ah[g]; const u16* __restrict__ Al = a.Al[g];
  const u16* __restrict__ Bh = a.Bh[g]; const u16* __restrict__ Bl = a.Bl[g];
  int t = threadIdx.x;
  int r0 = t>>2, k80 = (t&3)*8;
  int r1 = r0 + 64;
  int ar0 = m0 + r0; if(ar0 >= M) ar0 = M-1;
  int ar1 = m0 + r1; if(ar1 >= M) ar1 = M-1;
  const u16* Ap0h = Ah + (size_t)ar0*lda + k80;
  const u16* Ap1h = Ah + (size_t)ar1*lda + k80;
  const u16* Ap0l = Al + (size_t)ar0*lda + k80;
  const u16* Ap1l = Al + (size_t)ar1*lda + k80;
  const u16* Bp0h = Bh + (size_t)(n0+r0)*K + k80;
  const u16* Bp1h = Bh + (size_t)(n0+r1)*K + k80;
  const u16* Bp0l = Bl + (size_t)(n0+r0)*K + k80;
  const u16* Bp1l = Bl + (size_t)(n0+r1)*K + k80;
  int sA = r0*40 + k80;
  int sB = r1*40 + k80;

  int wave = t>>6, lane = t&63;
  int wr = wave>>1, wc = wave&1;
  int ml = lane&15, q = lane>>4;
  int aoff = (wr*64 + ml)*40 + q*8;
  int boff = (wc*64 + ml)*40 + q*8;

  float4v acc[4][4];
#pragma unroll
  for(int i=0;i<4;i++)
#pragma unroll
    for(int j=0;j<4;j++) acc[i][j] = 0.f;

  short8 cva[4], cvb[4];
  cva[0] = *(const short8*)(Ap0h); cva[1] = *(const short8*)(Ap1h);
  cva[2] = *(const short8*)(Ap0l); cva[3] = *(const short8*)(Ap1l);
  cvb[0] = *(const short8*)(Bp0h); cvb[1] = *(const short8*)(Bp1h);
  cvb[2] = *(const short8*)(Bp0l); cvb[3] = *(const short8*)(Bp1l);

  for(int k0=0; k0<K; k0+=32){
    __syncthreads();
    *(short8*)(Ash + sA) = cva[0];
    *(short8*)(Ash + sB) = cva[1];
    *(short8*)(Asl + sA) = cva[2];
    *(short8*)(Asl + sB) = cva[3];
    *(short8*)(Bsh + sA) = cvb[0];
    *(short8*)(Bsh + sB) = cvb[1];
    *(short8*)(Bsl + sA) = cvb[2];
    *(short8*)(Bsl + sB) = cvb[3];
    __syncthreads();
    short8 nva[4], nvb[4];
    bool more = (k0+32 < K);
    if(more){
      int kn = k0+32;
      nva[0] = *(const short8*)(Ap0h + kn); nva[1] = *(const short8*)(Ap1h + kn);
      nva[2] = *(const short8*)(Ap0l + kn); nva[3] = *(const short8*)(Ap1l + kn);
      nvb[0] = *(const short8*)(Bp0h + kn); nvb[1] = *(const short8*)(Bp1h + kn);
      nvb[2] = *(const short8*)(Bp0l + kn); nvb[3] = *(const short8*)(Bp1l + kn);
    }
    short8 afh[4], afl[4];
#pragma unroll
    for(int i=0;i<4;i++){
      afh[i] = *(const short8*)(Ash + aoff + i*640);
      afl[i] = *(const short8*)(Asl + aoff + i*640);
    }
#pragma unroll
    for(int j=0;j<4;j++){
      short8 bfh = *(const short8*)(Bsh + boff + j*640);
      short8 bfl = *(const short8*)(Bsl + boff + j*640);
#pragma unroll
      for(int i=0;i<4;i++){
        acc[i][j] = __builtin_amdgcn_mfma_f32_16x16x32_bf16(afh[i], bfh, acc[i][j], 0,0,0);
        acc[i][j] = __builtin_amdgcn_mfma_f32_16x16x32_bf16(afh[i], bfl, acc[i][j], 0,0,0);
        acc[i][j] = __builtin_amdgcn_mfma_f32_16x16x32_bf16(afl[i], bfh, acc[i][j], 0,0,0);
      }
    }
    if(more){
#pragma unroll
      for(int i=0;i<4;i++){ cva[i]=nva[i]; cvb[i]=nvb[i]; }
    }
  }
  const float* bias = a.bias[g];
  int split = a.split[g];
  float* C1 = a.C1[g]; float* C2 = a.C2[g];
  int ldc1 = a.ldc1[g], ldc2 = a.ldc2[g];
#pragma unroll
  for(int i=0;i<4;i++){
    int rowb = m0 + wr*64 + i*16 + q*4;
#pragma unroll
    for(int r=0;r<4;r++){
      int row = rowb + r;
      if(row < M){
#pragma unroll
        for(int j=0;j<4;j++){
          int col = n0 + wc*64 + j*16 + ml;
          float v = acc[i][j][r];
          if(bias) v += bias[col];
          if(col < split) C1[(size_t)row*ldc1 + col] = v;
          else            C2[(size_t)row*ldc2 + (col-split)] = v;
        }
      }
    }
  }
}

// ---------------- wigner apply + concat + PERM + rad scale -> msg1 split bf16 ----------------
__global__ __launch_bounds__(256) void wigner1_kernel(
    const float* __restrict__ x, const float* __restrict__ wigner,
    const int* __restrict__ src, const int* __restrict__ tgt,
    const float* __restrict__ rad, u16* __restrict__ msg1h, u16* __restrict__ msg1l){
  int e = blockIdx.x; int t = threadIdx.x;
  __shared__ float wig[625];
  __shared__ float4 cat4[1600];
  int s = src[e], tg = tgt[e];
  for(int i=t;i<625;i+=256) wig[i] = wigner[(size_t)e*625 + i];
  const float4* xs = (const float4*)(x + (size_t)s*3200);
  const float4* xt = (const float4*)(x + (size_t)tg*3200);
  for(int idx=t; idx<1600; idx+=256){
    int l = idx>>6, slot = idx&63;
    cat4[idx] = (slot<32) ? xs[l*32 + slot] : xt[l*32 + (slot-32)];
  }
  __syncthreads();
  int wave = t>>6, lane = t&63;
  for(int p=wave; p<25; p+=4){
    int pl = c_PERM[p];
    float4 acc = {0.f,0.f,0.f,0.f};
#pragma unroll
    for(int l=0;l<25;l++){
      float w = wig[pl*25 + l];
      float4 c = cat4[l*64 + lane];
      acc.x += w*c.x; acc.y += w*c.y; acc.z += w*c.z; acc.w += w*c.w;
    }
    float4 rd = *(const float4*)(rad + (size_t)e*3840 + c_ROFF[p] + lane*4);
    acc.x*=rd.x; acc.y*=rd.y; acc.z*=rd.z; acc.w*=rd.w;
    u16 h0,h1,h2,h3,l0,l1,l2,l3;
    bsplit(acc.x,h0,l0); bsplit(acc.y,h1,l1); bsplit(acc.z,h2,l2); bsplit(acc.w,h3,l3);
    size_t base = (size_t)e*6400 + p*256 + lane*4;
    *(uint2*)(msg1h + base) = make_uint2((unsigned)h0 | ((unsigned)h1<<16), (unsigned)h2 | ((unsigned)h3<<16));
    *(uint2*)(msg1l + base) = make_uint2((unsigned)l0 | ((unsigned)l1<<16), (unsigned)l2 | ((unsigned)l3<<16));
  }
}

// ---------------- grid gating -> msg_m2 split bf16 ----------------
__global__ __launch_bounds__(64) void grid_kernel(
    const float* __restrict__ msg2, const float* __restrict__ x0e,
    const float* __restrict__ tg, const float* __restrict__ fg,
    u16* __restrict__ m2h, u16* __restrict__ m2l){
  int e = blockIdx.x; int lane = threadIdx.x;
  float r[25];
#pragma unroll
  for(int i=0;i<25;i++) r[i] = msg2[((size_t)e*25 + INV_CE[i])*64 + lane];
  float s2[25];
#pragma unroll
  for(int i=0;i<25;i++) s2[i]=0.f;
  for(int g=0; g<100; g++){
    float tv=0.f;
#pragma unroll
    for(int i=0;i<25;i++) tv += tg[g*25+i]*r[i];
    tv = siluf(tv);
#pragma unroll
    for(int i=0;i<25;i++) s2[i] += fg[g*25+i]*tv;
  }
  float gate = siluf(x0e[(size_t)e*576 + 512 + lane]);
#pragma unroll
  for(int p=0;p<25;p++){
    int lp = PERM_CE[p];
    float v = (lp==0) ? gate : s2[lp];
    u16 h,l; bsplit(v,h,l);
    size_t idx = ((size_t)e*25+p)*64 + lane;
    m2h[idx]=h; m2l[idx]=l;
  }
}

// ---------------- alpha: LN + gate + logits -> ex=exp(logit), segsum atomics ----------------
__global__ __launch_bounds__(64) void alpha_kernel(
    const float* __restrict__ x0e, const float* __restrict__ g, const float* __restrict__ b,
    const float* __restrict__ adot, const int* __restrict__ tgt,
    float* __restrict__ exb, float* __restrict__ ssum){
  int e = blockIdx.x; int lane = threadIdx.x;
  int t = tgt[e];
  float gg = g[lane], bb = b[lane];
  for(int h=0;h<8;h++){
    float v = x0e[(size_t)e*576 + h*64 + lane];
    float mu = wsum64(v)*(1.f/64.f);
    float d = v-mu;
    float var = wsum64(d*d)*(1.f/64.f);
    float a = d*rsqrtf(var+1e-5f)*gg+bb;
    float sig = 1.f/(1.f+expf(-a));
    float a2 = 0.6f*a + 0.4f*a*(2.f*sig-1.f);
    float p = a2*adot[h*64+lane];
    float lg = wsum64(p);
    if(lane==0){
      float ex = expf(lg);
      exb[e*8+h]=ex;
      atomicAdd(&ssum[t*8+h], ex);
    }
  }
}

// ---------------- per-node aggregation: wigner^T transform + ex scale, no atomics ----------------
// block = node; walks chunk-local sorted edge list; node row accumulated in registers.
__global__ __launch_bounds__(256) void agg_kernel(
    const float* __restrict__ wigner_all, const float* __restrict__ msg3,
    const float* __restrict__ exb, const int* __restrict__ order,
    const int* __restrict__ basearr, const int* __restrict__ cnt,
    float* __restrict__ node, int e0){
  int n = blockIdx.x; int t = threadIdx.x;
  int lg = t>>5;   // 0..7
  int c4 = t&31;   // 0..31
  __shared__ float wig2[625];   // [q][l]
  __shared__ float m3s[3200];   // [q][c]
  float4v acc[4];
#pragma unroll
  for(int k=0;k<4;k++) acc[k] = 0.f;
  float* nb = node + (size_t)n*3200;
#pragma unroll
  for(int k=0;k<4;k++){ int l = lg + 8*k; if(l<25) acc[k] = *(const float4v*)(nb + l*128 + c4*4); }
  int nE = cnt[n], b0 = basearr[n];
  for(int j=0;j<nE;j++){
    int e = order[b0+j];
    int el = e - e0;
    __syncthreads();
    for(int i=t;i<625;i+=256){ int q=i/25, l=i%25; wig2[i] = wigner_all[((size_t)e*25 + c_PERM[q])*25 + l]; }
    for(int i=t;i<800;i+=256) ((float4*)m3s)[i] = ((const float4*)(msg3 + (size_t)el*3200))[i];
    __syncthreads();
    float ex = exb[el*8 + (c4>>2)];
    float4v tmp[4];
#pragma unroll
    for(int k=0;k<4;k++) tmp[k] = 0.f;
    for(int q=0;q<25;q++){
      float4v m = *(const float4v*)(m3s + q*128 + c4*4);
#pragma unroll
      for(int k=0;k<4;k++){
        int l = lg + 8*k;
        float w = (l<25) ? wig2[q*25 + l] : 0.f;
        tmp[k] += w*m;
      }
    }
#pragma unroll
    for(int k=0;k<4;k++) acc[k] += ex*tmp[k];
  }
#pragma unroll
  for(int k=0;k<4;k++){ int l = lg + 8*k; if(l<25) *(float4v*)(nb + l*128 + c4*4) = acc[k]; }
}

// ---------------- output projection (applies 1/segsum) ----------------
__global__ __launch_bounds__(256) void proj_kernel(
    const float* __restrict__ node, const float* __restrict__ ssum,
    const float* __restrict__ pwt, const float* __restrict__ proj_b,
    float* __restrict__ out, int NN){
  int n0 = blockIdx.x*2; int t = threadIdx.x;
  __shared__ float nd[2][3200];
  __shared__ float inv[2][8];
  if(t<16){
    int j=t>>3, h=t&7;
    int n=n0+j; if(n>=NN) n=NN-1;
    inv[j][h] = 1.f/(ssum[n*8+h] + 1e-16f);
  }
  __syncthreads();
  int n1 = (n0+1 < NN) ? (n0+1) : (NN-1);
  for(int i=t;i<3200;i+=256){
    int h = (i&127)>>4;
    nd[0][i] = node[(size_t)n0*3200 + i] * inv[0][h];
    nd[1][i] = node[(size_t)n1*3200 + i] * inv[1][h];
  }
  __syncthreads();
  int o = t&127, half = t>>7;
  for(int p=half;p<25;p+=2){
    int l = c_EXPAND[p];
    const float* w = pwt + l*16384;
    float a0=0.f, a1=0.f;
    for(int i=0;i<128;i++){
      float wv = w[i*128+o];
      a0 += nd[0][p*128+i]*wv;
      a1 += nd[1][p*128+i]*wv;
    }
    float bs = (p==0)? proj_b[o] : 0.f;
    out[((size_t)n0*25+p)*128 + o] = a0 + bs;
    if(n0+1 < NN) out[((size_t)(n0+1)*25+p)*128 + o] = a1 + bs;
  }
}

// ---------------- launcher ----------------
extern "C" void kernel_launch(void* const* d_in, const int* in_sizes, int n_in,
                              void* d_out, int out_size, void* d_ws, size_t ws_size,
                              hipStream_t stream) {
  const float* x           = (const float*)d_in[0];
  const float* edge_dist   = (const float*)d_in[1];
  const float* src_table   = (const float*)d_in[2];
  const float* tgt_table   = (const float*)d_in[3];
  const float* rad_w1      = (const float*)d_in[4];
  const float* rad_b1      = (const float*)d_in[5];
  const float* rad_ln1_g   = (const float*)d_in[6];
  const float* rad_ln1_b   = (const float*)d_in[7];
  const float* rad_w2      = (const float*)d_in[8];
  const float* rad_b2      = (const float*)d_in[9];
  const float* rad_ln2_g   = (const float*)d_in[10];
  const float* rad_ln2_b   = (const float*)d_in[11];
  const float* rad_w3      = (const float*)d_in[12];
  const float* rad_b3      = (const float*)d_in[13];
  const float* wigner      = (const float*)d_in[14];
  const float* c1_fc0_w    = (const float*)d_in[15];
  const float* c1_fc0_b    = (const float*)d_in[16];
  const float* c1_wm[4]    = {(const float*)d_in[17],(const float*)d_in[18],(const float*)d_in[19],(const float*)d_in[20]};
  const float* to_grid     = (const float*)d_in[21];
  const float* from_grid   = (const float*)d_in[22];
  const float* alpha_ln_g  = (const float*)d_in[23];
  const float* alpha_ln_b  = (const float*)d_in[24];
  const float* alpha_dot   = (const float*)d_in[25];
  const float* c2_fc0_w    = (const float*)d_in[26];
  const float* c2_fc0_b    = (const float*)d_in[27];
  const float* c2_wm[4]    = {(const float*)d_in[28],(const float*)d_in[29],(const float*)d_in[30],(const float*)d_in[31]};
  const float* proj_w      = (const float*)d_in[32];
  const float* proj_b      = (const float*)d_in[33];
  const int*   atomic_nums = (const int*)d_in[34];
  const int*   edge_index  = (const int*)d_in[35];
  float* out = (float*)d_out;
  (void)n_in; (void)out_size;

  const int E  = in_sizes[35]/2;   // 25000
  const int NN = in_sizes[34];     // 2500

  const int K1[4] = {1024, 768, 512, 256}, C1c[4] = {512, 384, 256, 128};
  const int K2[4] = {256, 192, 128, 64},  C2c[4] = {1024, 768, 512, 256};
  const size_t W3T = 3840*64;
  const size_t FC1 = 896*1280;
  const size_t W1S[4] = {512*2048, 384*1536, 256*1024, 128*512};
  const size_t FC2 = 640*320;
  const size_t W2S[4] = {1024*512, 768*384, 512*256, 256*128};
  size_t wush = 2*(W3T + FC1 + W1S[0]+W1S[1]+W1S[2]+W1S[3] + FC2 + W2S[0]+W2S[1]+W2S[2]+W2S[3]);
  const size_t persist = (size_t)NN*8 + (size_t)NN*3200 + wush/2 + 81920 + 4096;
  const size_t wfl = ws_size / sizeof(float);
  const int copts[10] = {25000, 12500, 6250, 5000, 3125, 2500, 1250, 625, 250, 125};
  int C = 125;
  for(int i=0;i<10;i++){
    size_t nchI = (size_t)((E + copts[i]-1)/copts[i]);
    size_t need = (size_t)copts[i]*(6400+3840+576+8) + persist + 3*nchI*NN + E;
    if(need <= wfl){ C = copts[i]; break; }
  }
  const int nch = (E + C - 1)/C;

  // --- workspace layout ---
  float* ws = (float*)d_ws;
  u16* msg1h = (u16*)ws;                          // C*6400 u16
  u16* msg1l = msg1h + (size_t)C*6400;
  u16* m2h   = (u16*)ws;                          // reuse: C*1600 u16
  u16* m2l   = m2h + (size_t)C*1600;
  float* msg3 = ws + (size_t)C*1600;              // C*3200 fl
  float* rad  = ws + (size_t)C*6400;              // C*3840 fl; later msg2
  float* msg2 = rad;
  float* x0e  = rad + (size_t)C*3840;             // C*576 fl; h2 split overlaid
  u16* h2h = (u16*)x0e;
  u16* h2l = h2h + (size_t)C*64;
  float* exb  = x0e + (size_t)C*576;              // C*8
  float* ssum = exb + (size_t)C*8;                // NN*8
  float* node = ssum + (size_t)NN*8;              // NN*3200
  u16* wb = (u16*)(node + (size_t)NN*3200);
  u16 *w3h = wb, *w3l = w3h + W3T;
  u16 *f1h = w3l + W3T, *f1l = f1h + FC1;
  u16 *w1h[4], *w1l[4];
  u16* p = f1l + FC1;
  for(int i=0;i<4;i++){ w1h[i]=p; w1l[i]=p+W1S[i]; p += 2*W1S[i]; }
  u16 *f2h = p, *f2l = f2h + FC2; p = f2l + FC2;
  u16 *w2h[4], *w2l[4];
  for(int i=0;i<4;i++){ w2h[i]=p; w2l[i]=p+W2S[i]; p += 2*W2S[i]; }
  float* pwt = (float*)p;
  int* cntb  = (int*)(pwt + 81920);
  int* baseb = cntb + (size_t)nch*NN;
  int* curb  = baseb + (size_t)nch*NN;
  int* order = curb + (size_t)nch*NN;

  hipMemsetAsync(node, 0, (size_t)NN*3200*sizeof(float), stream);
  hipMemsetAsync(ssum, 0, (size_t)NN*8*sizeof(float), stream);
  hipMemsetAsync(cntb, 0, (size_t)nch*NN*sizeof(int), stream);

  // --- edge sort by (chunk, tgt) ---
  const int* tgt_all = edge_index + E;
  hist_kernel<<<(E+255)/256, 256, 0, stream>>>(tgt_all, cntb, E, C, NN);
  scan_kernel<<<nch, 256, 0, stream>>>(cntb, baseb, curb, NN, C);
  scatter_kernel<<<(E+255)/256, 256, 0, stream>>>(tgt_all, curb, order, E, C, NN);

  // --- weight transforms ---
  fctrans_kernel<<<((int)W3T+255)/256, 256, 0, stream>>>(rad_w3, w3h, w3l, 64, 3840);
  fctrans_kernel<<<((int)FC1+255)/256, 256, 0, stream>>>(c1_fc0_w, f1h, f1l, 1280, 896);
  fctrans_kernel<<<((int)FC2+255)/256, 256, 0, stream>>>(c2_fc0_w, f2h, f2l, 320, 640);
  for(int i=0;i<4;i++)
    wtrans_kernel<<<((int)W1S[i]*2+255)/256, 256, 0, stream>>>(c1_wm[i], w1h[i], w1l[i], K1[i], C1c[i]);
  for(int i=0;i<4;i++)
    wtrans_kernel<<<((int)W2S[i]*2+255)/256, 256, 0, stream>>>(c2_wm[i], w2h[i], w2l[i], K2[i], C2c[i]);
  ptrans_kernel<<<320, 256, 0, stream>>>(proj_w, pwt);

  const int OFF1[4] = {5,13,19,23};
  for(int ch=0; ch<nch; ch++){
    int e0 = ch*C;
    int ce = (E - e0 < C) ? (E - e0) : C;
    const int* srcp = edge_index + e0;
    const int* tgtp = edge_index + E + e0;
    const float* wigp = wigner + (size_t)e0*625;
    int mt = (ce+127)/128;

    radial_kernel<<<ce, 64, 0, stream>>>(edge_dist + (size_t)e0*128, src_table, tgt_table,
        rad_w1, rad_b1, rad_ln1_g, rad_ln1_b, rad_w2, rad_b2, rad_ln2_g, rad_ln2_b,
        atomic_nums, srcp, tgtp, h2h, h2l);

    {
      GrpArgs ga = {};
      ga.ng = 1; ga.M = ce;
      ga.Ah[0]=h2h; ga.Al[0]=h2l; ga.Bh[0]=w3h; ga.Bl[0]=w3l;
      ga.bias[0]=rad_b3; ga.C1[0]=rad; ga.C2[0]=nullptr;
      ga.lda[0]=64; ga.K[0]=64; ga.ldc1[0]=3840; ga.ldc2[0]=0; ga.split[0]=3840;
      ga.xoff[0]=0; ga.xoff[1]=30;
      mgemm_kernel<<<dim3(30, mt), 256, 0, stream>>>(ga);
    }

    wigner1_kernel<<<ce, 256, 0, stream>>>(x, wigp, srcp, tgtp, rad, msg1h, msg1l);

    {
      GrpArgs ga = {};
      ga.ng = 5; ga.M = ce;
      ga.Ah[0]=msg1h; ga.Al[0]=msg1l; ga.Bh[0]=f1h; ga.Bl[0]=f1l;
      ga.bias[0]=c1_fc0_b; ga.C1[0]=x0e; ga.C2[0]=msg2;
      ga.lda[0]=6400; ga.K[0]=1280; ga.ldc1[0]=576; ga.ldc2[0]=1600; ga.split[0]=576;
      int xo = 7;
      ga.xoff[0]=0; ga.xoff[1]=7;
      for(int i=0;i<4;i++){
        int gidx = i+1;
        ga.Ah[gidx]=msg1h + (size_t)OFF1[i]*256; ga.Al[gidx]=msg1l + (size_t)OFF1[i]*256;
        ga.Bh[gidx]=w1h[i]; ga.Bl[gidx]=w1l[i];
        ga.bias[gidx]=nullptr; ga.C1[gidx]=msg2 + OFF1[i]*64; ga.C2[gidx]=nullptr;
        ga.lda[gidx]=6400; ga.K[gidx]=2*K1[i]; ga.ldc1[gidx]=1600; ga.ldc2[gidx]=0; ga.split[gidx]=C1c[i];
        xo += C1c[i]/128;
        ga.xoff[gidx+1]=xo;
      }
      mgemm_kernel<<<dim3(xo, mt), 256, 0, stream>>>(ga);
    }

    grid_kernel<<<ce, 64, 0, stream>>>(msg2, x0e, to_grid, from_grid, m2h, m2l);
    alpha_kernel<<<ce, 64, 0, stream>>>(x0e, alpha_ln_g, alpha_ln_b, alpha_dot, tgtp, exb, ssum);

    {
      GrpArgs ga = {};
      ga.ng = 5; ga.M = ce;
      ga.Ah[0]=m2h; ga.Al[0]=m2l; ga.Bh[0]=f2h; ga.Bl[0]=f2l;
      ga.bias[0]=c2_fc0_b; ga.C1[0]=msg3; ga.C2[0]=nullptr;
      ga.lda[0]=1600; ga.K[0]=320; ga.ldc1[0]=3200; ga.ldc2[0]=0; ga.split[0]=640;
      int xo = 5;
      ga.xoff[0]=0; ga.xoff[1]=5;
      for(int i=0;i<4;i++){
        int gidx = i+1;
        ga.Ah[gidx]=m2h + (size_t)OFF1[i]*64; ga.Al[gidx]=m2l + (size_t)OFF1[i]*64;
        ga.Bh[gidx]=w2h[i]; ga.Bl[gidx]=w2l[i];
        ga.bias[gidx]=nullptr; ga.C1[gidx]=msg3 + OFF1[i]*128; ga.C2[gidx]=nullptr;
        ga.lda[gidx]=1600; ga.K[gidx]=2*K2[i]; ga.ldc1[gidx]=3200; ga.ldc2[gidx]=0; ga.split[gidx]=C2c[i];
        xo += C2c[i]/128;
        ga.xoff[gidx+1]=xo;
      }
      mgemm_kernel<<<dim3(xo, mt), 256, 0, stream>>>(ga);
    }

    agg_kernel<<<NN, 256, 0, stream>>>(wigner, msg3, exb, order,
        baseb + (size_t)ch*NN, cntb + (size_t)ch*NN, node, e0);
  }

  proj_kernel<<<(NN+1)/2, 256, 0, stream>>>(node, ssum, pwt, proj_b, out, NN);
}

// Round 5
// 3584.798 us; speedup vs baseline: 3.6978x; 1.0214x over previous
//
#include <hip/hip_runtime.h>
#include <cstddef>

typedef unsigned short u16;
typedef __attribute__((ext_vector_type(8))) short short8;
typedef __attribute__((ext_vector_type(4))) float float4v;

// ---------------- constants ----------------
__constant__ int c_PERM[25] = {0,2,6,12,20, 1,5,11,19, 3,7,13,21, 4,10,18, 8,14,22, 9,17, 15,23, 16,24};
__constant__ int c_ROFF[25] = {0,256,512,768,1024, 1280,1536,1792,2048, 1280,1536,1792,2048,
                               2304,2560,2816, 2304,2560,2816, 3072,3328, 3072,3328, 3584,3584};
__constant__ int c_EXPAND[25] = {0,1,1,1,2,2,2,2,2,3,3,3,3,3,3,3,4,4,4,4,4,4,4,4,4};

static constexpr int PERM_CE[25] = {0,2,6,12,20, 1,5,11,19, 3,7,13,21, 4,10,18, 8,14,22, 9,17, 15,23, 16,24};
static constexpr int INV_CE[25]  = {0,5,1,9,13, 6,2,10,16,19, 14,7,3,11,17, 21,23,20,15,8, 4,12,18,22,24};

__device__ __forceinline__ float wsum64(float v){
#pragma unroll
  for(int m=32;m>0;m>>=1) v += __shfl_xor(v, m, 64);
  return v;
}
__device__ __forceinline__ float siluf(float x){ return x/(1.f+expf(-x)); }

__device__ __forceinline__ void bsplit(float v, u16 &h, u16 &l){
  unsigned u = __float_as_uint(v);
  unsigned hb = (u + 0x7FFFu + ((u>>16)&1u)) >> 16;
  h = (u16)hb;
  float r = v - __uint_as_float(hb<<16);
  unsigned u2 = __float_as_uint(r);
  l = (u16)((u2 + 0x7FFFu + ((u2>>16)&1u)) >> 16);
}

// ---------------- weight transforms ----------------
__global__ __launch_bounds__(256) void wtrans_kernel(const float* __restrict__ W, u16* __restrict__ Wh, u16* __restrict__ Wl, int K, int C2){
  int idx = blockIdx.x*256 + threadIdx.x;
  int K2 = 2*K;
  if(idx >= C2*K2) return;
  int n = idx / K2, k2 = idx % K2;
  int half = C2>>1;
  float v;
  if(k2 < K) v = W[k2*C2 + n];
  else { int k = k2-K; v = (n<half) ? -W[k*C2 + half + n] : W[k*C2 + n - half]; }
  u16 h,l; bsplit(v,h,l);
  Wh[idx]=h; Wl[idx]=l;
}

__global__ __launch_bounds__(256) void fctrans_kernel(const float* __restrict__ W, u16* __restrict__ Wh, u16* __restrict__ Wl, int K, int N){
  int idx = blockIdx.x*256 + threadIdx.x;
  if(idx >= N*K) return;
  int n = idx / K, k = idx % K;
  u16 h,l; bsplit(W[(size_t)k*N + n],h,l);
  Wh[idx]=h; Wl[idx]=l;
}

__global__ __launch_bounds__(256) void ptrans_kernel(const float* __restrict__ pw, float* __restrict__ pwt){
  int idx = blockIdx.x*256+threadIdx.x;
  if(idx >= 5*16384) return;
  int l = idx>>14, r = idx & 16383, i = r>>7, o = r&127;
  pwt[idx] = pw[(l<<14) + (o<<7) + i];
}

// ---------------- edge sort by target (per chunk) ----------------
__global__ __launch_bounds__(256) void hist_kernel(const int* __restrict__ tgt_all, int* __restrict__ cnt, int E, int C, int NN){
  int idx = blockIdx.x*256+threadIdx.x;
  if(idx>=E) return;
  atomicAdd(&cnt[(idx/C)*NN + tgt_all[idx]], 1);
}
__global__ __launch_bounds__(256) void scan_kernel(const int* __restrict__ cnt, int* __restrict__ basearr, int* __restrict__ cur, int NN, int C){
  int ch = blockIdx.x;
  __shared__ int sh[256];
  __shared__ int carry;
  if(threadIdx.x==0) carry = ch*C;
  __syncthreads();
  for(int t0=0; t0<NN; t0+=256){
    int i = t0 + threadIdx.x;
    int v = (i<NN)? cnt[ch*NN+i] : 0;
    sh[threadIdx.x]=v; __syncthreads();
    for(int off=1; off<256; off<<=1){
      int add = (threadIdx.x>=off)? sh[threadIdx.x-off]:0; __syncthreads();
      sh[threadIdx.x]+=add; __syncthreads();
    }
    int excl = carry + sh[threadIdx.x]-v;
    if(i<NN){ basearr[ch*NN+i]=excl; cur[ch*NN+i]=excl; }
    __syncthreads();
    if(threadIdx.x==255) carry += sh[255];
    __syncthreads();
  }
}
__global__ __launch_bounds__(256) void scatter_kernel(const int* __restrict__ tgt_all, int* __restrict__ cur, int* __restrict__ order, int E, int C, int NN){
  int idx = blockIdx.x*256+threadIdx.x;
  if(idx>=E) return;
  int ch = idx / C;
  int pos = atomicAdd(&cur[ch*NN + tgt_all[idx]], 1);
  order[pos] = idx;
}

// ---------------- radial MLP -> h2 split bf16 ----------------
__global__ __launch_bounds__(64) void radial_kernel(
    const float* __restrict__ ed, const float* __restrict__ st, const float* __restrict__ tt,
    const float* __restrict__ w1, const float* __restrict__ b1, const float* __restrict__ g1, const float* __restrict__ bb1,
    const float* __restrict__ w2, const float* __restrict__ b2, const float* __restrict__ g2, const float* __restrict__ bb2,
    const int* __restrict__ an, const int* __restrict__ src, const int* __restrict__ tgt,
    u16* __restrict__ h2h, u16* __restrict__ h2l){
  int e = blockIdx.x; int lane = threadIdx.x;
  __shared__ float xe[256];
  __shared__ float h1s[64];
  int s = src[e], t = tgt[e];
  xe[lane]      = ed[(size_t)e*128 + lane];
  xe[64+lane]   = ed[(size_t)e*128 + 64 + lane];
  int as = an[s], at = an[t];
  xe[128+lane]  = st[as*64 + lane];
  xe[192+lane]  = tt[at*64 + lane];
  __syncthreads();
  float acc = b1[lane];
  for(int k=0;k<256;k++) acc += xe[k]*w1[k*64+lane];
  float mu = wsum64(acc)*(1.f/64.f);
  float d = acc - mu;
  float var = wsum64(d*d)*(1.f/64.f);
  float nrm = d*rsqrtf(var+1e-5f)*g1[lane]+bb1[lane];
  h1s[lane] = siluf(nrm);
  __syncthreads();
  float acc2 = b2[lane];
  for(int k=0;k<64;k++) acc2 += h1s[k]*w2[k*64+lane];
  mu = wsum64(acc2)*(1.f/64.f);
  d = acc2-mu;
  var = wsum64(d*d)*(1.f/64.f);
  nrm = d*rsqrtf(var+1e-5f)*g2[lane]+bb2[lane];
  u16 h,l; bsplit(siluf(nrm),h,l);
  h2h[(size_t)e*64+lane]=h; h2l[(size_t)e*64+lane]=l;
}

// ---------------- grouped split-bf16 MFMA GEMM ----------------
// XCD-swizzled 1D grid, LDS double-buffered, XOR-swizzled banks.
struct GrpArgs {
  const u16* Ah[6]; const u16* Al[6];
  const u16* Bh[6]; const u16* Bl[6];
  const float* bias[6]; float* C1[6]; float* C2[6];
  int lda[6]; int K[6]; int ldc1[6]; int ldc2[6]; int split[6];
  int xoff[7]; int ng; int M; int gx; int gy;
};

__global__ __launch_bounds__(256) void mgemm_kernel(GrpArgs a){
  // [buf][row][col] 128 rows x 32 u16, xor-swizzled col-blocks of 8 u16
  __shared__ __align__(16) u16 Ash[2][4096];
  __shared__ __align__(16) u16 Asl[2][4096];
  __shared__ __align__(16) u16 Bsh[2][4096];
  __shared__ __align__(16) u16 Bsl[2][4096];

  // XCD swizzle: xcd = b&7 owns contiguous x-tile subset, sweeps x fast / y slow
  int b = blockIdx.x;
  int xcd = b & 7, i = b >> 3;
  int pbase = a.gx >> 3, prem = a.gx & 7;
  int s = pbase + (xcd < prem ? 1 : 0);
  if(i >= s * a.gy) return;
  int o = xcd*pbase + (xcd < prem ? xcd : prem);
  int xt = o + (i % s);
  int yt = i / s;

  int g = 0;
  while(g+1 < a.ng && xt >= a.xoff[g+1]) g++;
  int n0 = (xt - a.xoff[g])*128, m0 = yt*128;
  const int M = a.M, K = a.K[g], lda = a.lda[g];
  const u16* __restrict__ Ah = a.Ah[g]; const u16* __restrict__ Al = a.Al[g];
  const u16* __restrict__ Bh = a.Bh[g]; const u16* __restrict__ Bl = a.Bl[g];
  int t = threadIdx.x;
  int r0 = t>>2, kblk = t&3, k80 = kblk*8;
  int ar0 = m0 + r0; if(ar0 >= M) ar0 = M-1;
  int ar1 = m0 + r0 + 64; if(ar1 >= M) ar1 = M-1;
  const u16* Ap0h = Ah + (size_t)ar0*lda + k80;
  const u16* Ap1h = Ah + (size_t)ar1*lda + k80;
  const u16* Ap0l = Al + (size_t)ar0*lda + k80;
  const u16* Ap1l = Al + (size_t)ar1*lda + k80;
  const u16* Bp0h = Bh + (size_t)(n0+r0)*K + k80;
  const u16* Bp1h = Bh + (size_t)(n0+r0+64)*K + k80;
  const u16* Bp0l = Bl + (size_t)(n0+r0)*K + k80;
  const u16* Bp1l = Bl + (size_t)(n0+r0+64)*K + k80;
  // store addr: row*32 + (kblk ^ ((row>>1)&3))*8 ; same pcb for row and row+64
  int pcbS = kblk ^ ((r0>>1)&3);
  int sA = r0*32 + pcbS*8;
  int sB = sA + 64*32;

  int wave = t>>6, lane = t&63;
  int wr = wave>>1, wc = wave&1;
  int ml = lane&15, q = lane>>4;
  int pcbA = q ^ ((ml>>1)&3);
  int aoff = (wr*64 + ml)*32 + pcbA*8;   // + i*16*32
  int boff = (wc*64 + ml)*32 + pcbA*8;

  float4v acc[4][4];
#pragma unroll
  for(int i2=0;i2<4;i2++)
#pragma unroll
    for(int j=0;j<4;j++) acc[i2][j] = 0.f;

  short8 cva[4], cvb[4];
  cva[0] = *(const short8*)(Ap0h); cva[1] = *(const short8*)(Ap1h);
  cva[2] = *(const short8*)(Ap0l); cva[3] = *(const short8*)(Ap1l);
  cvb[0] = *(const short8*)(Bp0h); cvb[1] = *(const short8*)(Bp1h);
  cvb[2] = *(const short8*)(Bp0l); cvb[3] = *(const short8*)(Bp1l);

  int p = 0;
  for(int k0=0; k0<K; k0+=32){
    // store current prefetch into LDS[p]
    *(short8*)(&Ash[p][sA]) = cva[0];
    *(short8*)(&Ash[p][sB]) = cva[1];
    *(short8*)(&Asl[p][sA]) = cva[2];
    *(short8*)(&Asl[p][sB]) = cva[3];
    *(short8*)(&Bsh[p][sA]) = cvb[0];
    *(short8*)(&Bsh[p][sB]) = cvb[1];
    *(short8*)(&Bsl[p][sA]) = cvb[2];
    *(short8*)(&Bsl[p][sB]) = cvb[3];
    // issue next prefetch (in flight across the whole compute phase)
    if(k0+32 < K){
      int kn = k0+32;
      cva[0] = *(const short8*)(Ap0h + kn); cva[1] = *(const short8*)(Ap1h + kn);
      cva[2] = *(const short8*)(Ap0l + kn); cva[3] = *(const short8*)(Ap1l + kn);
      cvb[0] = *(const short8*)(Bp0h + kn); cvb[1] = *(const short8*)(Bp1h + kn);
      cvb[2] = *(const short8*)(Bp0l + kn); cvb[3] = *(const short8*)(Bp1l + kn);
    }
    __syncthreads();
    short8 afh[4], afl[4];
#pragma unroll
    for(int i2=0;i2<4;i2++){
      afh[i2] = *(const short8*)(&Ash[p][aoff + i2*512]);
      afl[i2] = *(const short8*)(&Asl[p][aoff + i2*512]);
    }
#pragma unroll
    for(int j=0;j<4;j++){
      short8 bfh = *(const short8*)(&Bsh[p][boff + j*512]);
      short8 bfl = *(const short8*)(&Bsl[p][boff + j*512]);
#pragma unroll
      for(int i2=0;i2<4;i2++){
        acc[i2][j] = __builtin_amdgcn_mfma_f32_16x16x32_bf16(afh[i2], bfh, acc[i2][j], 0,0,0);
        acc[i2][j] = __builtin_amdgcn_mfma_f32_16x16x32_bf16(afh[i2], bfl, acc[i2][j], 0,0,0);
        acc[i2][j] = __builtin_amdgcn_mfma_f32_16x16x32_bf16(afl[i2], bfh, acc[i2][j], 0,0,0);
      }
    }
    p ^= 1;
  }
  const float* bias = a.bias[g];
  int split = a.split[g];
  float* C1 = a.C1[g]; float* C2 = a.C2[g];
  int ldc1 = a.ldc1[g], ldc2 = a.ldc2[g];
#pragma unroll
  for(int i2=0;i2<4;i2++){
    int rowb = m0 + wr*64 + i2*16 + q*4;
#pragma unroll
    for(int r=0;r<4;r++){
      int row = rowb + r;
      if(row < M){
#pragma unroll
        for(int j=0;j<4;j++){
          int col = n0 + wc*64 + j*16 + ml;
          float v = acc[i2][j][r];
          if(bias) v += bias[col];
          if(col < split) C1[(size_t)row*ldc1 + col] = v;
          else            C2[(size_t)row*ldc2 + (col-split)] = v;
        }
      }
    }
  }
}

// ---------------- wigner apply + concat + PERM + rad scale -> msg1 split bf16 ----------------
__global__ __launch_bounds__(256) void wigner1_kernel(
    const float* __restrict__ x, const float* __restrict__ wigner,
    const int* __restrict__ src, const int* __restrict__ tgt,
    const float* __restrict__ rad, u16* __restrict__ msg1h, u16* __restrict__ msg1l){
  int e = blockIdx.x; int t = threadIdx.x;
  __shared__ float wig[625];
  __shared__ float4 cat4[1600];
  int s = src[e], tg = tgt[e];
  for(int i=t;i<625;i+=256) wig[i] = wigner[(size_t)e*625 + i];
  const float4* xs = (const float4*)(x + (size_t)s*3200);
  const float4* xt = (const float4*)(x + (size_t)tg*3200);
  for(int idx=t; idx<1600; idx+=256){
    int l = idx>>6, slot = idx&63;
    cat4[idx] = (slot<32) ? xs[l*32 + slot] : xt[l*32 + (slot-32)];
  }
  __syncthreads();
  int wave = t>>6, lane = t&63;
  for(int p=wave; p<25; p+=4){
    int pl = c_PERM[p];
    float4 acc = {0.f,0.f,0.f,0.f};
#pragma unroll
    for(int l=0;l<25;l++){
      float w = wig[pl*25 + l];
      float4 c = cat4[l*64 + lane];
      acc.x += w*c.x; acc.y += w*c.y; acc.z += w*c.z; acc.w += w*c.w;
    }
    float4 rd = *(const float4*)(rad + (size_t)e*3840 + c_ROFF[p] + lane*4);
    acc.x*=rd.x; acc.y*=rd.y; acc.z*=rd.z; acc.w*=rd.w;
    u16 h0,h1,h2,h3,l0,l1,l2,l3;
    bsplit(acc.x,h0,l0); bsplit(acc.y,h1,l1); bsplit(acc.z,h2,l2); bsplit(acc.w,h3,l3);
    size_t base = (size_t)e*6400 + p*256 + lane*4;
    *(uint2*)(msg1h + base) = make_uint2((unsigned)h0 | ((unsigned)h1<<16), (unsigned)h2 | ((unsigned)h3<<16));
    *(uint2*)(msg1l + base) = make_uint2((unsigned)l0 | ((unsigned)l1<<16), (unsigned)l2 | ((unsigned)l3<<16));
  }
}

// ---------------- grid gating -> msg_m2 split bf16 ----------------
__global__ __launch_bounds__(64) void grid_kernel(
    const float* __restrict__ msg2, const float* __restrict__ x0e,
    const float* __restrict__ tg, const float* __restrict__ fg,
    u16* __restrict__ m2h, u16* __restrict__ m2l){
  int e = blockIdx.x; int lane = threadIdx.x;
  float r[25];
#pragma unroll
  for(int i=0;i<25;i++) r[i] = msg2[((size_t)e*25 + INV_CE[i])*64 + lane];
  float s2[25];
#pragma unroll
  for(int i=0;i<25;i++) s2[i]=0.f;
  for(int g=0; g<100; g++){
    float tv=0.f;
#pragma unroll
    for(int i=0;i<25;i++) tv += tg[g*25+i]*r[i];
    tv = siluf(tv);
#pragma unroll
    for(int i=0;i<25;i++) s2[i] += fg[g*25+i]*tv;
  }
  float gate = siluf(x0e[(size_t)e*576 + 512 + lane]);
#pragma unroll
  for(int p=0;p<25;p++){
    int lp = PERM_CE[p];
    float v = (lp==0) ? gate : s2[lp];
    u16 h,l; bsplit(v,h,l);
    size_t idx = ((size_t)e*25+p)*64 + lane;
    m2h[idx]=h; m2l[idx]=l;
  }
}

// ---------------- alpha ----------------
__global__ __launch_bounds__(64) void alpha_kernel(
    const float* __restrict__ x0e, const float* __restrict__ g, const float* __restrict__ b,
    const float* __restrict__ adot, const int* __restrict__ tgt,
    float* __restrict__ exb, float* __restrict__ ssum){
  int e = blockIdx.x; int lane = threadIdx.x;
  int t = tgt[e];
  float gg = g[lane], bb = b[lane];
  for(int h=0;h<8;h++){
    float v = x0e[(size_t)e*576 + h*64 + lane];
    float mu = wsum64(v)*(1.f/64.f);
    float d = v-mu;
    float var = wsum64(d*d)*(1.f/64.f);
    float a = d*rsqrtf(var+1e-5f)*gg+bb;
    float sig = 1.f/(1.f+expf(-a));
    float a2 = 0.6f*a + 0.4f*a*(2.f*sig-1.f);
    float p = a2*adot[h*64+lane];
    float lg = wsum64(p);
    if(lane==0){
      float ex = expf(lg);
      exb[e*8+h]=ex;
      atomicAdd(&ssum[t*8+h], ex);
    }
  }
}

// ---------------- per-node aggregation ----------------
__global__ __launch_bounds__(256) void agg_kernel(
    const float* __restrict__ wigner_all, const float* __restrict__ msg3,
    const float* __restrict__ exb, const int* __restrict__ order,
    const int* __restrict__ basearr, const int* __restrict__ cnt,
    float* __restrict__ node, int e0){
  int n = blockIdx.x; int t = threadIdx.x;
  int lg = t>>5;
  int c4 = t&31;
  __shared__ float wig2[625];
  __shared__ float m3s[3200];
  float4v acc[4];
#pragma unroll
  for(int k=0;k<4;k++) acc[k] = 0.f;
  float* nb = node + (size_t)n*3200;
#pragma unroll
  for(int k=0;k<4;k++){ int l = lg + 8*k; if(l<25) acc[k] = *(const float4v*)(nb + l*128 + c4*4); }
  int nE = cnt[n], b0 = basearr[n];
  for(int j=0;j<nE;j++){
    int e = order[b0+j];
    int el = e - e0;
    __syncthreads();
    for(int i=t;i<625;i+=256){ int q=i/25, l=i%25; wig2[i] = wigner_all[((size_t)e*25 + c_PERM[q])*25 + l]; }
    for(int i=t;i<800;i+=256) ((float4*)m3s)[i] = ((const float4*)(msg3 + (size_t)el*3200))[i];
    __syncthreads();
    float ex = exb[el*8 + (c4>>2)];
    float4v tmp[4];
#pragma unroll
    for(int k=0;k<4;k++) tmp[k] = 0.f;
    for(int q=0;q<25;q++){
      float4v m = *(const float4v*)(m3s + q*128 + c4*4);
#pragma unroll
      for(int k=0;k<4;k++){
        int l = lg + 8*k;
        float w = (l<25) ? wig2[q*25 + l] : 0.f;
        tmp[k] += w*m;
      }
    }
#pragma unroll
    for(int k=0;k<4;k++) acc[k] += ex*tmp[k];
  }
#pragma unroll
  for(int k=0;k<4;k++){ int l = lg + 8*k; if(l<25) *(float4v*)(nb + l*128 + c4*4) = acc[k]; }
}

// ---------------- output projection ----------------
__global__ __launch_bounds__(256) void proj_kernel(
    const float* __restrict__ node, const float* __restrict__ ssum,
    const float* __restrict__ pwt, const float* __restrict__ proj_b,
    float* __restrict__ out, int NN){
  int n0 = blockIdx.x*2; int t = threadIdx.x;
  __shared__ float nd[2][3200];
  __shared__ float inv[2][8];
  if(t<16){
    int j=t>>3, h=t&7;
    int n=n0+j; if(n>=NN) n=NN-1;
    inv[j][h] = 1.f/(ssum[n*8+h] + 1e-16f);
  }
  __syncthreads();
  int n1 = (n0+1 < NN) ? (n0+1) : (NN-1);
  for(int i=t;i<3200;i+=256){
    int h = (i&127)>>4;
    nd[0][i] = node[(size_t)n0*3200 + i] * inv[0][h];
    nd[1][i] = node[(size_t)n1*3200 + i] * inv[1][h];
  }
  __syncthreads();
  int o = t&127, half = t>>7;
  for(int p=half;p<25;p+=2){
    int l = c_EXPAND[p];
    const float* w = pwt + l*16384;
    float a0=0.f, a1=0.f;
    for(int i=0;i<128;i++){
      float wv = w[i*128+o];
      a0 += nd[0][p*128+i]*wv;
      a1 += nd[1][p*128+i]*wv;
    }
    float bs = (p==0)? proj_b[o] : 0.f;
    out[((size_t)n0*25+p)*128 + o] = a0 + bs;
    if(n0+1 < NN) out[((size_t)(n0+1)*25+p)*128 + o] = a1 + bs;
  }
}

// ---------------- launcher ----------------
extern "C" void kernel_launch(void* const* d_in, const int* in_sizes, int n_in,
                              void* d_out, int out_size, void* d_ws, size_t ws_size,
                              hipStream_t stream) {
  const float* x           = (const float*)d_in[0];
  const float* edge_dist   = (const float*)d_in[1];
  const float* src_table   = (const float*)d_in[2];
  const float* tgt_table   = (const float*)d_in[3];
  const float* rad_w1      = (const float*)d_in[4];
  const float* rad_b1      = (const float*)d_in[5];
  const float* rad_ln1_g   = (const float*)d_in[6];
  const float* rad_ln1_b   = (const float*)d_in[7];
  const float* rad_w2      = (const float*)d_in[8];
  const float* rad_b2      = (const float*)d_in[9];
  const float* rad_ln2_g   = (const float*)d_in[10];
  const float* rad_ln2_b   = (const float*)d_in[11];
  const float* rad_w3      = (const float*)d_in[12];
  const float* rad_b3      = (const float*)d_in[13];
  const float* wigner      = (const float*)d_in[14];
  const float* c1_fc0_w    = (const float*)d_in[15];
  const float* c1_fc0_b    = (const float*)d_in[16];
  const float* c1_wm[4]    = {(const float*)d_in[17],(const float*)d_in[18],(const float*)d_in[19],(const float*)d_in[20]};
  const float* to_grid     = (const float*)d_in[21];
  const float* from_grid   = (const float*)d_in[22];
  const float* alpha_ln_g  = (const float*)d_in[23];
  const float* alpha_ln_b  = (const float*)d_in[24];
  const float* alpha_dot   = (const float*)d_in[25];
  const float* c2_fc0_w    = (const float*)d_in[26];
  const float* c2_fc0_b    = (const float*)d_in[27];
  const float* c2_wm[4]    = {(const float*)d_in[28],(const float*)d_in[29],(const float*)d_in[30],(const float*)d_in[31]};
  const float* proj_w      = (const float*)d_in[32];
  const float* proj_b      = (const float*)d_in[33];
  const int*   atomic_nums = (const int*)d_in[34];
  const int*   edge_index  = (const int*)d_in[35];
  float* out = (float*)d_out;
  (void)n_in; (void)out_size;

  const int E  = in_sizes[35]/2;   // 25000
  const int NN = in_sizes[34];     // 2500

  const int K1[4] = {1024, 768, 512, 256}, C1c[4] = {512, 384, 256, 128};
  const int K2[4] = {256, 192, 128, 64},  C2c[4] = {1024, 768, 512, 256};
  const size_t W3T = 3840*64;
  const size_t FC1 = 896*1280;
  const size_t W1S[4] = {512*2048, 384*1536, 256*1024, 128*512};
  const size_t FC2 = 640*320;
  const size_t W2S[4] = {1024*512, 768*384, 512*256, 256*128};
  size_t wush = 2*(W3T + FC1 + W1S[0]+W1S[1]+W1S[2]+W1S[3] + FC2 + W2S[0]+W2S[1]+W2S[2]+W2S[3]);
  const size_t persist = (size_t)NN*8 + (size_t)NN*3200 + wush/2 + 81920 + 8192;
  const size_t wfl = ws_size / sizeof(float);
  const int copts[10] = {25000, 12500, 6250, 5000, 3125, 2500, 1250, 625, 250, 125};
  int C = 125;
  for(int i=0;i<10;i++){
    size_t nchI = (size_t)((E + copts[i]-1)/copts[i]);
    size_t hc = (size_t)(copts[i]+1)/2;
    size_t need = (size_t)copts[i]*(6400+576+8) + hc*3840 + persist + 3*nchI*NN + E;
    if(need <= wfl){ C = copts[i]; break; }
  }
  const int nch = (E + C - 1)/C;
  const size_t halfC = (size_t)(C+1)/2;

  // --- workspace layout ---
  float* ws = (float*)d_ws;
  u16* msg1h = (u16*)ws;                          // C*6400 u16
  u16* msg1l = msg1h + (size_t)C*6400;
  u16* m2h   = (u16*)ws;                          // reuse: C*1600 u16
  u16* m2l   = m2h + (size_t)C*1600;
  float* msg3 = ws + (size_t)C*1600;              // C*3200 fl (within msg1 region)
  float* rad  = ws + (size_t)C*6400;              // halfC*3840 fl; later msg2 (C*1600 fl <= halfC*3840)
  float* msg2 = rad;
  float* x0e  = rad + halfC*3840;                 // C*576 fl; h2 split overlaid
  u16* h2h = (u16*)x0e;
  u16* h2l = h2h + halfC*64;
  float* exb  = x0e + (size_t)C*576;              // C*8
  float* ssum = exb + (size_t)C*8;                // NN*8
  float* node = ssum + (size_t)NN*8;              // NN*3200
  u16* wb = (u16*)(node + (size_t)NN*3200);
  u16 *w3h = wb, *w3l = w3h + W3T;
  u16 *f1h = w3l + W3T, *f1l = f1h + FC1;
  u16 *w1h[4], *w1l[4];
  u16* p = f1l + FC1;
  for(int i=0;i<4;i++){ w1h[i]=p; w1l[i]=p+W1S[i]; p += 2*W1S[i]; }
  u16 *f2h = p, *f2l = f2h + FC2; p = f2l + FC2;
  u16 *w2h[4], *w2l[4];
  for(int i=0;i<4;i++){ w2h[i]=p; w2l[i]=p+W2S[i]; p += 2*W2S[i]; }
  float* pwt = (float*)p;
  int* cntb  = (int*)(pwt + 81920);
  int* baseb = cntb + (size_t)nch*NN;
  int* curb  = baseb + (size_t)nch*NN;
  int* order = curb + (size_t)nch*NN;

  hipMemsetAsync(node, 0, (size_t)NN*3200*sizeof(float), stream);
  hipMemsetAsync(ssum, 0, (size_t)NN*8*sizeof(float), stream);
  hipMemsetAsync(cntb, 0, (size_t)nch*NN*sizeof(int), stream);

  // --- edge sort by (chunk, tgt) ---
  const int* tgt_all = edge_index + E;
  hist_kernel<<<(E+255)/256, 256, 0, stream>>>(tgt_all, cntb, E, C, NN);
  scan_kernel<<<nch, 256, 0, stream>>>(cntb, baseb, curb, NN, C);
  scatter_kernel<<<(E+255)/256, 256, 0, stream>>>(tgt_all, curb, order, E, C, NN);

  // --- weight transforms ---
  fctrans_kernel<<<((int)W3T+255)/256, 256, 0, stream>>>(rad_w3, w3h, w3l, 64, 3840);
  fctrans_kernel<<<((int)FC1+255)/256, 256, 0, stream>>>(c1_fc0_w, f1h, f1l, 1280, 896);
  fctrans_kernel<<<((int)FC2+255)/256, 256, 0, stream>>>(c2_fc0_w, f2h, f2l, 320, 640);
  for(int i=0;i<4;i++)
    wtrans_kernel<<<((int)W1S[i]*2+255)/256, 256, 0, stream>>>(c1_wm[i], w1h[i], w1l[i], K1[i], C1c[i]);
  for(int i=0;i<4;i++)
    wtrans_kernel<<<((int)W2S[i]*2+255)/256, 256, 0, stream>>>(c2_wm[i], w2h[i], w2l[i], K2[i], C2c[i]);
  ptrans_kernel<<<320, 256, 0, stream>>>(proj_w, pwt);

  auto launchM = [&](GrpArgs &ga, int gx, int gy){
    ga.gx = gx; ga.gy = gy;
    int base = gx>>3, rem = gx&7;
    int maxs = base + (rem?1:0);
    mgemm_kernel<<<8*maxs*gy, 256, 0, stream>>>(ga);
  };

  const int OFF1[4] = {5,13,19,23};
  for(int ch=0; ch<nch; ch++){
    int e0 = ch*C;
    int ce = (E - e0 < C) ? (E - e0) : C;
    const int* srcp = edge_index + e0;
    const int* tgtp = edge_index + E + e0;
    const float* wigp = wigner + (size_t)e0*625;
    int mt = (ce+127)/128;

    // radial + rad GEMM + wigner1 in two half-chunks (rad buffer is halfC)
    int half1 = (ce+1)/2;
    for(int hh=0; hh<2; hh++){
      int h0 = hh ? half1 : 0;
      int he = hh ? (ce - half1) : half1;
      if(he <= 0) continue;
      radial_kernel<<<he, 64, 0, stream>>>(edge_dist + (size_t)(e0+h0)*128, src_table, tgt_table,
          rad_w1, rad_b1, rad_ln1_g, rad_ln1_b, rad_w2, rad_b2, rad_ln2_g, rad_ln2_b,
          atomic_nums, srcp+h0, tgtp+h0, h2h, h2l);
      {
        GrpArgs ga = {};
        ga.ng = 1; ga.M = he;
        ga.Ah[0]=h2h; ga.Al[0]=h2l; ga.Bh[0]=w3h; ga.Bl[0]=w3l;
        ga.bias[0]=rad_b3; ga.C1[0]=rad; ga.C2[0]=nullptr;
        ga.lda[0]=64; ga.K[0]=64; ga.ldc1[0]=3840; ga.ldc2[0]=0; ga.split[0]=3840;
        ga.xoff[0]=0; ga.xoff[1]=30;
        launchM(ga, 30, (he+127)/128);
      }
      wigner1_kernel<<<he, 256, 0, stream>>>(x, wigp + (size_t)h0*625, srcp+h0, tgtp+h0, rad,
          msg1h + (size_t)h0*6400, msg1l + (size_t)h0*6400);
    }

    // conv1 grouped: fc0 + 4 m-blocks
    {
      GrpArgs ga = {};
      ga.ng = 5; ga.M = ce;
      ga.Ah[0]=msg1h; ga.Al[0]=msg1l; ga.Bh[0]=f1h; ga.Bl[0]=f1l;
      ga.bias[0]=c1_fc0_b; ga.C1[0]=x0e; ga.C2[0]=msg2;
      ga.lda[0]=6400; ga.K[0]=1280; ga.ldc1[0]=576; ga.ldc2[0]=1600; ga.split[0]=576;
      int xo = 7;
      ga.xoff[0]=0; ga.xoff[1]=7;
      for(int i=0;i<4;i++){
        int gidx = i+1;
        ga.Ah[gidx]=msg1h + (size_t)OFF1[i]*256; ga.Al[gidx]=msg1l + (size_t)OFF1[i]*256;
        ga.Bh[gidx]=w1h[i]; ga.Bl[gidx]=w1l[i];
        ga.bias[gidx]=nullptr; ga.C1[gidx]=msg2 + OFF1[i]*64; ga.C2[gidx]=nullptr;
        ga.lda[gidx]=6400; ga.K[gidx]=2*K1[i]; ga.ldc1[gidx]=1600; ga.ldc2[gidx]=0; ga.split[gidx]=C1c[i];
        xo += C1c[i]/128;
        ga.xoff[gidx+1]=xo;
      }
      launchM(ga, xo, mt);
    }

    grid_kernel<<<ce, 64, 0, stream>>>(msg2, x0e, to_grid, from_grid, m2h, m2l);
    alpha_kernel<<<ce, 64, 0, stream>>>(x0e, alpha_ln_g, alpha_ln_b, alpha_dot, tgtp, exb, ssum);

    // conv2 grouped: fc0 + 4 m-blocks
    {
      GrpArgs ga = {};
      ga.ng = 5; ga.M = ce;
      ga.Ah[0]=m2h; ga.Al[0]=m2l; ga.Bh[0]=f2h; ga.Bl[0]=f2l;
      ga.bias[0]=c2_fc0_b; ga.C1[0]=msg3; ga.C2[0]=nullptr;
      ga.lda[0]=1600; ga.K[0]=320; ga.ldc1[0]=3200; ga.ldc2[0]=0; ga.split[0]=640;
      int xo = 5;
      ga.xoff[0]=0; ga.xoff[1]=5;
      for(int i=0;i<4;i++){
        int gidx = i+1;
        ga.Ah[gidx]=m2h + (size_t)OFF1[i]*64; ga.Al[gidx]=m2l + (size_t)OFF1[i]*64;
        ga.Bh[gidx]=w2h[i]; ga.Bl[gidx]=w2l[i];
        ga.bias[gidx]=nullptr; ga.C1[gidx]=msg3 + OFF1[i]*128; ga.C2[gidx]=nullptr;
        ga.lda[gidx]=1600; ga.K[gidx]=2*K2[i]; ga.ldc1[gidx]=3200; ga.ldc2[gidx]=0; ga.split[gidx]=C2c[i];
        xo += C2c[i]/128;
        ga.xoff[gidx+1]=xo;
      }
      launchM(ga, xo, mt);
    }

    agg_kernel<<<NN, 256, 0, stream>>>(wigner, msg3, exb, order,
        baseb + (size_t)ch*NN, cntb + (size_t)ch*NN, node, e0);
  }

  proj_kernel<<<(NN+1)/2, 256, 0, stream>>>(node, ssum, pwt, proj_b, out, NN);
}

// Round 6
// 3540.175 us; speedup vs baseline: 3.7444x; 1.0126x over previous
//
#include <hip/hip_runtime.h>
#include <cstddef>

typedef unsigned short u16;
typedef __attribute__((ext_vector_type(8))) short short8;
typedef __attribute__((ext_vector_type(4))) float float4v;

// ---------------- constants ----------------
__constant__ int c_PERM[25] = {0,2,6,12,20, 1,5,11,19, 3,7,13,21, 4,10,18, 8,14,22, 9,17, 15,23, 16,24};
__constant__ int c_ROFF[25] = {0,256,512,768,1024, 1280,1536,1792,2048, 1280,1536,1792,2048,
                               2304,2560,2816, 2304,2560,2816, 3072,3328, 3072,3328, 3584,3584};
__constant__ int c_EXPAND[25] = {0,1,1,1,2,2,2,2,2,3,3,3,3,3,3,3,4,4,4,4,4,4,4,4,4};

static constexpr int PERM_CE[25] = {0,2,6,12,20, 1,5,11,19, 3,7,13,21, 4,10,18, 8,14,22, 9,17, 15,23, 16,24};
static constexpr int INV_CE[25]  = {0,5,1,9,13, 6,2,10,16,19, 14,7,3,11,17, 21,23,20,15,8, 4,12,18,22,24};

__device__ __forceinline__ float wsum64(float v){
#pragma unroll
  for(int m=32;m>0;m>>=1) v += __shfl_xor(v, m, 64);
  return v;
}
__device__ __forceinline__ float siluf(float x){ return x/(1.f+expf(-x)); }

__device__ __forceinline__ void bsplit(float v, u16 &h, u16 &l){
  unsigned u = __float_as_uint(v);
  unsigned hb = (u + 0x7FFFu + ((u>>16)&1u)) >> 16;
  h = (u16)hb;
  float r = v - __uint_as_float(hb<<16);
  unsigned u2 = __float_as_uint(r);
  l = (u16)((u2 + 0x7FFFu + ((u2>>16)&1u)) >> 16);
}

// ---------------- weight transforms ----------------
__global__ __launch_bounds__(256) void wtrans_kernel(const float* __restrict__ W, u16* __restrict__ Wh, u16* __restrict__ Wl, int K, int C2){
  int idx = blockIdx.x*256 + threadIdx.x;
  int K2 = 2*K;
  if(idx >= C2*K2) return;
  int n = idx / K2, k2 = idx % K2;
  int half = C2>>1;
  float v;
  if(k2 < K) v = W[k2*C2 + n];
  else { int k = k2-K; v = (n<half) ? -W[k*C2 + half + n] : W[k*C2 + n - half]; }
  u16 h,l; bsplit(v,h,l);
  Wh[idx]=h; Wl[idx]=l;
}

__global__ __launch_bounds__(256) void fctrans_kernel(const float* __restrict__ W, u16* __restrict__ Wh, u16* __restrict__ Wl, int K, int N){
  int idx = blockIdx.x*256 + threadIdx.x;
  if(idx >= N*K) return;
  int n = idx / K, k = idx % K;
  u16 h,l; bsplit(W[(size_t)k*N + n],h,l);
  Wh[idx]=h; Wl[idx]=l;
}

__global__ __launch_bounds__(256) void ptrans_kernel(const float* __restrict__ pw, float* __restrict__ pwt){
  int idx = blockIdx.x*256+threadIdx.x;
  if(idx >= 5*16384) return;
  int l = idx>>14, r = idx & 16383, i = r>>7, o = r&127;
  pwt[idx] = pw[(l<<14) + (o<<7) + i];
}

// ---------------- GLOBAL edge sort by target ----------------
__global__ __launch_bounds__(256) void hist_kernel(const int* __restrict__ tgt_all, int* __restrict__ cnt, int E){
  int idx = blockIdx.x*256+threadIdx.x;
  if(idx>=E) return;
  atomicAdd(&cnt[tgt_all[idx]], 1);
}
__global__ __launch_bounds__(256) void scan_kernel(const int* __restrict__ cnt, int* __restrict__ basearr, int* __restrict__ cur, int NN){
  __shared__ int sh[256];
  __shared__ int carry;
  if(threadIdx.x==0) carry = 0;
  __syncthreads();
  for(int t0=0; t0<NN; t0+=256){
    int i = t0 + threadIdx.x;
    int v = (i<NN)? cnt[i] : 0;
    sh[threadIdx.x]=v; __syncthreads();
    for(int off=1; off<256; off<<=1){
      int add = (threadIdx.x>=off)? sh[threadIdx.x-off]:0; __syncthreads();
      sh[threadIdx.x]+=add; __syncthreads();
    }
    int excl = carry + sh[threadIdx.x]-v;
    if(i<NN){ basearr[i]=excl; cur[i]=excl; }
    __syncthreads();
    if(threadIdx.x==255) carry += sh[255];
    __syncthreads();
  }
}
__global__ __launch_bounds__(256) void scatter_kernel(const int* __restrict__ ei, int* __restrict__ cur,
    int* __restrict__ order, int* __restrict__ srcs, int* __restrict__ tgts, int E){
  int idx = blockIdx.x*256+threadIdx.x;
  if(idx>=E) return;
  int t = ei[E+idx];
  int pos = atomicAdd(&cur[t], 1);
  order[pos] = idx;
  tgts[pos] = t;
  srcs[pos] = ei[idx];
}

// ---------------- radial MLP -> h2 split bf16 (sorted order, gathers ed via order) ----------------
__global__ __launch_bounds__(64) void radial_kernel(
    const float* __restrict__ ed, const float* __restrict__ st, const float* __restrict__ tt,
    const float* __restrict__ w1, const float* __restrict__ b1, const float* __restrict__ g1, const float* __restrict__ bb1,
    const float* __restrict__ w2, const float* __restrict__ b2, const float* __restrict__ g2, const float* __restrict__ bb2,
    const int* __restrict__ an, const int* __restrict__ order,
    const int* __restrict__ src, const int* __restrict__ tgt,
    u16* __restrict__ h2h, u16* __restrict__ h2l){
  int e = blockIdx.x; int lane = threadIdx.x;
  __shared__ float xe[256];
  __shared__ float h1s[64];
  int eo = order[e];
  int s = src[e], t = tgt[e];
  xe[lane]      = ed[(size_t)eo*128 + lane];
  xe[64+lane]   = ed[(size_t)eo*128 + 64 + lane];
  int as = an[s], at = an[t];
  xe[128+lane]  = st[as*64 + lane];
  xe[192+lane]  = tt[at*64 + lane];
  __syncthreads();
  float acc = b1[lane];
  for(int k=0;k<256;k++) acc += xe[k]*w1[k*64+lane];
  float mu = wsum64(acc)*(1.f/64.f);
  float d = acc - mu;
  float var = wsum64(d*d)*(1.f/64.f);
  float nrm = d*rsqrtf(var+1e-5f)*g1[lane]+bb1[lane];
  h1s[lane] = siluf(nrm);
  __syncthreads();
  float acc2 = b2[lane];
  for(int k=0;k<64;k++) acc2 += h1s[k]*w2[k*64+lane];
  mu = wsum64(acc2)*(1.f/64.f);
  d = acc2-mu;
  var = wsum64(d*d)*(1.f/64.f);
  nrm = d*rsqrtf(var+1e-5f)*g2[lane]+bb2[lane];
  u16 h,l; bsplit(siluf(nrm),h,l);
  h2h[(size_t)e*64+lane]=h; h2l[(size_t)e*64+lane]=l;
}

// ---------------- grouped split-bf16 MFMA GEMM ----------------
// store -> barrier -> prefetch-next -> compute : prefetch latency hidden by MFMA phase.
struct GrpArgs {
  const u16* Ah[6]; const u16* Al[6];
  const u16* Bh[6]; const u16* Bl[6];
  const float* bias[6]; float* C1[6]; float* C2[6];
  int lda[6]; int K[6]; int ldc1[6]; int ldc2[6]; int split[6];
  int xoff[7]; int ng; int M; int gx; int gy;
};

__global__ __launch_bounds__(256) void mgemm_kernel(GrpArgs a){
  __shared__ __align__(16) u16 Ash[2][4096];
  __shared__ __align__(16) u16 Asl[2][4096];
  __shared__ __align__(16) u16 Bsh[2][4096];
  __shared__ __align__(16) u16 Bsl[2][4096];

  int b = blockIdx.x;
  int xcd = b & 7, i = b >> 3;
  int pbase = a.gx >> 3, prem = a.gx & 7;
  int s = pbase + (xcd < prem ? 1 : 0);
  if(i >= s * a.gy) return;
  int o = xcd*pbase + (xcd < prem ? xcd : prem);
  int xt = o + (i % s);
  int yt = i / s;

  int g = 0;
  while(g+1 < a.ng && xt >= a.xoff[g+1]) g++;
  int n0 = (xt - a.xoff[g])*128, m0 = yt*128;
  const int M = a.M, K = a.K[g], lda = a.lda[g];
  const u16* __restrict__ Ah = a.Ah[g]; const u16* __restrict__ Al = a.Al[g];
  const u16* __restrict__ Bh = a.Bh[g]; const u16* __restrict__ Bl = a.Bl[g];
  int t = threadIdx.x;
  int r0 = t>>2, kblk = t&3, k80 = kblk*8;
  int ar0 = m0 + r0; if(ar0 >= M) ar0 = M-1;
  int ar1 = m0 + r0 + 64; if(ar1 >= M) ar1 = M-1;
  const u16* Ap0h = Ah + (size_t)ar0*lda + k80;
  const u16* Ap1h = Ah + (size_t)ar1*lda + k80;
  const u16* Ap0l = Al + (size_t)ar0*lda + k80;
  const u16* Ap1l = Al + (size_t)ar1*lda + k80;
  const u16* Bp0h = Bh + (size_t)(n0+r0)*K + k80;
  const u16* Bp1h = Bh + (size_t)(n0+r0+64)*K + k80;
  const u16* Bp0l = Bl + (size_t)(n0+r0)*K + k80;
  const u16* Bp1l = Bl + (size_t)(n0+r0+64)*K + k80;
  int pcbS = kblk ^ ((r0>>1)&3);
  int sA = r0*32 + pcbS*8;
  int sB = sA + 64*32;

  int wave = t>>6, lane = t&63;
  int wr = wave>>1, wc = wave&1;
  int ml = lane&15, q = lane>>4;
  int pcbA = q ^ ((ml>>1)&3);
  int aoff = (wr*64 + ml)*32 + pcbA*8;
  int boff = (wc*64 + ml)*32 + pcbA*8;

  float4v acc[4][4];
#pragma unroll
  for(int i2=0;i2<4;i2++)
#pragma unroll
    for(int j=0;j<4;j++) acc[i2][j] = 0.f;

  short8 cva[4], cvb[4];
  cva[0] = *(const short8*)(Ap0h); cva[1] = *(const short8*)(Ap1h);
  cva[2] = *(const short8*)(Ap0l); cva[3] = *(const short8*)(Ap1l);
  cvb[0] = *(const short8*)(Bp0h); cvb[1] = *(const short8*)(Bp1h);
  cvb[2] = *(const short8*)(Bp0l); cvb[3] = *(const short8*)(Bp1l);

  int p = 0;
  for(int k0=0; k0<K; k0+=32){
    // store current prefetch into LDS[p]
    *(short8*)(&Ash[p][sA]) = cva[0];
    *(short8*)(&Ash[p][sB]) = cva[1];
    *(short8*)(&Asl[p][sA]) = cva[2];
    *(short8*)(&Asl[p][sB]) = cva[3];
    *(short8*)(&Bsh[p][sA]) = cvb[0];
    *(short8*)(&Bsh[p][sB]) = cvb[1];
    *(short8*)(&Bsl[p][sA]) = cvb[2];
    *(short8*)(&Bsl[p][sB]) = cvb[3];
    __syncthreads();
    // prefetch NEXT step AFTER the barrier: in flight during the whole MFMA phase,
    // first waited on at next iteration's LDS store.
    if(k0+32 < K){
      int kn = k0+32;
      cva[0] = *(const short8*)(Ap0h + kn); cva[1] = *(const short8*)(Ap1h + kn);
      cva[2] = *(const short8*)(Ap0l + kn); cva[3] = *(const short8*)(Ap1l + kn);
      cvb[0] = *(const short8*)(Bp0h + kn); cvb[1] = *(const short8*)(Bp1h + kn);
      cvb[2] = *(const short8*)(Bp0l + kn); cvb[3] = *(const short8*)(Bp1l + kn);
    }
    short8 afh[4], afl[4];
#pragma unroll
    for(int i2=0;i2<4;i2++){
      afh[i2] = *(const short8*)(&Ash[p][aoff + i2*512]);
      afl[i2] = *(const short8*)(&Asl[p][aoff + i2*512]);
    }
#pragma unroll
    for(int j=0;j<4;j++){
      short8 bfh = *(const short8*)(&Bsh[p][boff + j*512]);
      short8 bfl = *(const short8*)(&Bsl[p][boff + j*512]);
#pragma unroll
      for(int i2=0;i2<4;i2++){
        acc[i2][j] = __builtin_amdgcn_mfma_f32_16x16x32_bf16(afh[i2], bfh, acc[i2][j], 0,0,0);
        acc[i2][j] = __builtin_amdgcn_mfma_f32_16x16x32_bf16(afh[i2], bfl, acc[i2][j], 0,0,0);
        acc[i2][j] = __builtin_amdgcn_mfma_f32_16x16x32_bf16(afl[i2], bfh, acc[i2][j], 0,0,0);
      }
    }
    p ^= 1;
  }
  const float* bias = a.bias[g];
  int split = a.split[g];
  float* C1 = a.C1[g]; float* C2 = a.C2[g];
  int ldc1 = a.ldc1[g], ldc2 = a.ldc2[g];
#pragma unroll
  for(int i2=0;i2<4;i2++){
    int rowb = m0 + wr*64 + i2*16 + q*4;
#pragma unroll
    for(int r=0;r<4;r++){
      int row = rowb + r;
      if(row < M){
#pragma unroll
        for(int j=0;j<4;j++){
          int col = n0 + wc*64 + j*16 + ml;
          float v = acc[i2][j][r];
          if(bias) v += bias[col];
          if(col < split) C1[(size_t)row*ldc1 + col] = v;
          else            C2[(size_t)row*ldc2 + (col-split)] = v;
        }
      }
    }
  }
}

// ---------------- wigner apply (sorted order) -> msg1 split bf16 ----------------
__global__ __launch_bounds__(256) void wigner1_kernel(
    const float* __restrict__ x, const float* __restrict__ wigner_all,
    const int* __restrict__ order, const int* __restrict__ src, const int* __restrict__ tgt,
    const float* __restrict__ rad, u16* __restrict__ msg1h, u16* __restrict__ msg1l){
  int e = blockIdx.x; int t = threadIdx.x;
  __shared__ float wig[625];
  __shared__ float4 cat4[1600];
  int eo = order[e];
  int s = src[e], tg = tgt[e];
  for(int i=t;i<625;i+=256) wig[i] = wigner_all[(size_t)eo*625 + i];
  const float4* xs = (const float4*)(x + (size_t)s*3200);
  const float4* xt = (const float4*)(x + (size_t)tg*3200);
  for(int idx=t; idx<1600; idx+=256){
    int l = idx>>6, slot = idx&63;
    cat4[idx] = (slot<32) ? xs[l*32 + slot] : xt[l*32 + (slot-32)];
  }
  __syncthreads();
  int wave = t>>6, lane = t&63;
  for(int p=wave; p<25; p+=4){
    int pl = c_PERM[p];
    float4 acc = {0.f,0.f,0.f,0.f};
#pragma unroll
    for(int l=0;l<25;l++){
      float w = wig[pl*25 + l];
      float4 c = cat4[l*64 + lane];
      acc.x += w*c.x; acc.y += w*c.y; acc.z += w*c.z; acc.w += w*c.w;
    }
    float4 rd = *(const float4*)(rad + (size_t)e*3840 + c_ROFF[p] + lane*4);
    acc.x*=rd.x; acc.y*=rd.y; acc.z*=rd.z; acc.w*=rd.w;
    u16 h0,h1,h2,h3,l0,l1,l2,l3;
    bsplit(acc.x,h0,l0); bsplit(acc.y,h1,l1); bsplit(acc.z,h2,l2); bsplit(acc.w,h3,l3);
    size_t base = (size_t)e*6400 + p*256 + lane*4;
    *(uint2*)(msg1h + base) = make_uint2((unsigned)h0 | ((unsigned)h1<<16), (unsigned)h2 | ((unsigned)h3<<16));
    *(uint2*)(msg1l + base) = make_uint2((unsigned)l0 | ((unsigned)l1<<16), (unsigned)l2 | ((unsigned)l3<<16));
  }
}

// ---------------- grid gating -> msg_m2 split bf16 ----------------
__global__ __launch_bounds__(64) void grid_kernel(
    const float* __restrict__ msg2, const float* __restrict__ x0e,
    const float* __restrict__ tg, const float* __restrict__ fg,
    u16* __restrict__ m2h, u16* __restrict__ m2l){
  int e = blockIdx.x; int lane = threadIdx.x;
  float r[25];
#pragma unroll
  for(int i=0;i<25;i++) r[i] = msg2[((size_t)e*25 + INV_CE[i])*64 + lane];
  float s2[25];
#pragma unroll
  for(int i=0;i<25;i++) s2[i]=0.f;
  for(int g=0; g<100; g++){
    float tv=0.f;
#pragma unroll
    for(int i=0;i<25;i++) tv += tg[g*25+i]*r[i];
    tv = siluf(tv);
#pragma unroll
    for(int i=0;i<25;i++) s2[i] += fg[g*25+i]*tv;
  }
  float gate = siluf(x0e[(size_t)e*576 + 512 + lane]);
#pragma unroll
  for(int p=0;p<25;p++){
    int lp = PERM_CE[p];
    float v = (lp==0) ? gate : s2[lp];
    u16 h,l; bsplit(v,h,l);
    size_t idx = ((size_t)e*25+p)*64 + lane;
    m2h[idx]=h; m2l[idx]=l;
  }
}

// ---------------- alpha ----------------
__global__ __launch_bounds__(64) void alpha_kernel(
    const float* __restrict__ x0e, const float* __restrict__ g, const float* __restrict__ b,
    const float* __restrict__ adot, const int* __restrict__ tgt,
    float* __restrict__ exb, float* __restrict__ ssum){
  int e = blockIdx.x; int lane = threadIdx.x;
  int t = tgt[e];
  float gg = g[lane], bb = b[lane];
  for(int h=0;h<8;h++){
    float v = x0e[(size_t)e*576 + h*64 + lane];
    float mu = wsum64(v)*(1.f/64.f);
    float d = v-mu;
    float var = wsum64(d*d)*(1.f/64.f);
    float a = d*rsqrtf(var+1e-5f)*gg+bb;
    float sig = 1.f/(1.f+expf(-a));
    float a2 = 0.6f*a + 0.4f*a*(2.f*sig-1.f);
    float p = a2*adot[h*64+lane];
    float lg = wsum64(p);
    if(lane==0){
      float ex = expf(lg);
      exb[e*8+h]=ex;
      atomicAdd(&ssum[t*8+h], ex);
    }
  }
}

// ---------------- per-node aggregation (global sort: nodes contiguous per chunk) ----------------
__global__ __launch_bounds__(256) void agg_kernel(
    const float* __restrict__ wigner_all, const float* __restrict__ msg3,
    const float* __restrict__ exb, const int* __restrict__ order,
    const int* __restrict__ basearr, const int* __restrict__ cnt,
    float* __restrict__ node, int e0, int e1){
  int n = blockIdx.x; int t = threadIdx.x;
  int b0 = basearr[n], c = cnt[n];
  int lo = b0 > e0 ? b0 : e0;
  int hi = (b0+c) < e1 ? (b0+c) : e1;
  if(lo >= hi) return;
  int lg = t>>5;
  int c4 = t&31;
  __shared__ float wig2[625];
  __shared__ float m3s[3200];
  float4v acc[4];
#pragma unroll
  for(int k=0;k<4;k++) acc[k] = 0.f;
  float* nb = node + (size_t)n*3200;
#pragma unroll
  for(int k=0;k<4;k++){ int l = lg + 8*k; if(l<25) acc[k] = *(const float4v*)(nb + l*128 + c4*4); }
  for(int j=lo;j<hi;j++){
    int e = order[j];
    int el = j - e0;
    __syncthreads();
    for(int i=t;i<625;i+=256){ int q=i/25, l=i%25; wig2[i] = wigner_all[((size_t)e*25 + c_PERM[q])*25 + l]; }
    for(int i=t;i<800;i+=256) ((float4*)m3s)[i] = ((const float4*)(msg3 + (size_t)el*3200))[i];
    __syncthreads();
    float ex = exb[el*8 + (c4>>2)];
    float4v tmp[4];
#pragma unroll
    for(int k=0;k<4;k++) tmp[k] = 0.f;
    for(int q=0;q<25;q++){
      float4v m = *(const float4v*)(m3s + q*128 + c4*4);
#pragma unroll
      for(int k=0;k<4;k++){
        int l = lg + 8*k;
        float w = (l<25) ? wig2[q*25 + l] : 0.f;
        tmp[k] += w*m;
      }
    }
#pragma unroll
    for(int k=0;k<4;k++) acc[k] += ex*tmp[k];
  }
#pragma unroll
  for(int k=0;k<4;k++){ int l = lg + 8*k; if(l<25) *(float4v*)(nb + l*128 + c4*4) = acc[k]; }
}

// ---------------- output projection ----------------
__global__ __launch_bounds__(256) void proj_kernel(
    const float* __restrict__ node, const float* __restrict__ ssum,
    const float* __restrict__ pwt, const float* __restrict__ proj_b,
    float* __restrict__ out, int NN){
  int n0 = blockIdx.x*2; int t = threadIdx.x;
  __shared__ float nd[2][3200];
  __shared__ float inv[2][8];
  if(t<16){
    int j=t>>3, h=t&7;
    int n=n0+j; if(n>=NN) n=NN-1;
    inv[j][h] = 1.f/(ssum[n*8+h] + 1e-16f);
  }
  __syncthreads();
  int n1 = (n0+1 < NN) ? (n0+1) : (NN-1);
  for(int i=t;i<3200;i+=256){
    int h = (i&127)>>4;
    nd[0][i] = node[(size_t)n0*3200 + i] * inv[0][h];
    nd[1][i] = node[(size_t)n1*3200 + i] * inv[1][h];
  }
  __syncthreads();
  int o = t&127, half = t>>7;
  for(int p=half;p<25;p+=2){
    int l = c_EXPAND[p];
    const float* w = pwt + l*16384;
    float a0=0.f, a1=0.f;
    for(int i=0;i<128;i++){
      float wv = w[i*128+o];
      a0 += nd[0][p*128+i]*wv;
      a1 += nd[1][p*128+i]*wv;
    }
    float bs = (p==0)? proj_b[o] : 0.f;
    out[((size_t)n0*25+p)*128 + o] = a0 + bs;
    if(n0+1 < NN) out[((size_t)(n0+1)*25+p)*128 + o] = a1 + bs;
  }
}

// ---------------- launcher ----------------
extern "C" void kernel_launch(void* const* d_in, const int* in_sizes, int n_in,
                              void* d_out, int out_size, void* d_ws, size_t ws_size,
                              hipStream_t stream) {
  const float* x           = (const float*)d_in[0];
  const float* edge_dist   = (const float*)d_in[1];
  const float* src_table   = (const float*)d_in[2];
  const float* tgt_table   = (const float*)d_in[3];
  const float* rad_w1      = (const float*)d_in[4];
  const float* rad_b1      = (const float*)d_in[5];
  const float* rad_ln1_g   = (const float*)d_in[6];
  const float* rad_ln1_b   = (const float*)d_in[7];
  const float* rad_w2      = (const float*)d_in[8];
  const float* rad_b2      = (const float*)d_in[9];
  const float* rad_ln2_g   = (const float*)d_in[10];
  const float* rad_ln2_b   = (const float*)d_in[11];
  const float* rad_w3      = (const float*)d_in[12];
  const float* rad_b3      = (const float*)d_in[13];
  const float* wigner      = (const float*)d_in[14];
  const float* c1_fc0_w    = (const float*)d_in[15];
  const float* c1_fc0_b    = (const float*)d_in[16];
  const float* c1_wm[4]    = {(const float*)d_in[17],(const float*)d_in[18],(const float*)d_in[19],(const float*)d_in[20]};
  const float* to_grid     = (const float*)d_in[21];
  const float* from_grid   = (const float*)d_in[22];
  const float* alpha_ln_g  = (const float*)d_in[23];
  const float* alpha_ln_b  = (const float*)d_in[24];
  const float* alpha_dot   = (const float*)d_in[25];
  const float* c2_fc0_w    = (const float*)d_in[26];
  const float* c2_fc0_b    = (const float*)d_in[27];
  const float* c2_wm[4]    = {(const float*)d_in[28],(const float*)d_in[29],(const float*)d_in[30],(const float*)d_in[31]};
  const float* proj_w      = (const float*)d_in[32];
  const float* proj_b      = (const float*)d_in[33];
  const int*   atomic_nums = (const int*)d_in[34];
  const int*   edge_index  = (const int*)d_in[35];
  float* out = (float*)d_out;
  (void)n_in; (void)out_size;

  const int E  = in_sizes[35]/2;   // 25000
  const int NN = in_sizes[34];     // 2500

  const int K1[4] = {1024, 768, 512, 256}, C1c[4] = {512, 384, 256, 128};
  const int K2[4] = {256, 192, 128, 64},  C2c[4] = {1024, 768, 512, 256};
  const size_t W3T = 3840*64;
  const size_t FC1 = 896*1280;
  const size_t W1S[4] = {512*2048, 384*1536, 256*1024, 128*512};
  const size_t FC2 = 640*320;
  const size_t W2S[4] = {1024*512, 768*384, 512*256, 256*128};
  const size_t WSUM = W3T + FC1 + W1S[0]+W1S[1]+W1S[2]+W1S[3] + FC2 + W2S[0]+W2S[1]+W2S[2]+W2S[3];
  // exact persist accounting (floats)
  const size_t persist = (size_t)NN*8 + (size_t)NN*3200 + WSUM /* 2*WSUM u16 = WSUM fl */
                       + 81920 + (size_t)3*NN + (size_t)3*E + 8192;
  const size_t wfl = ws_size / sizeof(float);
  const int copts[10] = {25000, 12500, 6250, 5000, 3125, 2500, 1250, 625, 250, 125};
  int C = 125;
  for(int i=0;i<10;i++){
    size_t hc = (size_t)(copts[i]+1)/2;
    size_t need = (size_t)copts[i]*(6400+576+8) + hc*3840 + persist;
    if(need <= wfl){ C = copts[i]; break; }
  }
  const int nch = (E + C - 1)/C;
  const size_t halfC = (size_t)(C+1)/2;

  // --- workspace layout ---
  float* ws = (float*)d_ws;
  u16* msg1h = (u16*)ws;                          // C*6400 u16
  u16* msg1l = msg1h + (size_t)C*6400;
  u16* m2h   = (u16*)ws;                          // reuse: C*1600 u16
  u16* m2l   = m2h + (size_t)C*1600;
  float* msg3 = ws + (size_t)C*1600;              // C*3200 fl
  float* rad  = ws + (size_t)C*6400;              // halfC*3840 fl; later msg2 (C*1600 fl)
  float* msg2 = rad;
  float* x0e  = rad + halfC*3840;                 // C*576 fl; h2 split overlaid
  u16* h2h = (u16*)x0e;
  u16* h2l = h2h + halfC*64;
  float* exb  = x0e + (size_t)C*576;              // C*8
  float* ssum = exb + (size_t)C*8;                // NN*8
  float* node = ssum + (size_t)NN*8;              // NN*3200
  u16* wb = (u16*)(node + (size_t)NN*3200);
  u16 *w3h = wb, *w3l = w3h + W3T;
  u16 *f1h = w3l + W3T, *f1l = f1h + FC1;
  u16 *w1h[4], *w1l[4];
  u16* p = f1l + FC1;
  for(int i=0;i<4;i++){ w1h[i]=p; w1l[i]=p+W1S[i]; p += 2*W1S[i]; }
  u16 *f2h = p, *f2l = f2h + FC2; p = f2l + FC2;
  u16 *w2h[4], *w2l[4];
  for(int i=0;i<4;i++){ w2h[i]=p; w2l[i]=p+W2S[i]; p += 2*W2S[i]; }
  float* pwt = (float*)p;
  int* cntb  = (int*)(pwt + 81920);   // NN
  int* baseb = cntb + NN;             // NN
  int* curb  = baseb + NN;            // NN
  int* order = curb + NN;             // E
  int* srcs  = order + E;             // E
  int* tgts  = srcs + E;              // E

  hipMemsetAsync(node, 0, (size_t)NN*3200*sizeof(float), stream);
  hipMemsetAsync(ssum, 0, (size_t)NN*8*sizeof(float), stream);
  hipMemsetAsync(cntb, 0, (size_t)NN*sizeof(int), stream);

  // --- GLOBAL edge sort by target ---
  hist_kernel<<<(E+255)/256, 256, 0, stream>>>(edge_index + E, cntb, E);
  scan_kernel<<<1, 256, 0, stream>>>(cntb, baseb, curb, NN);
  scatter_kernel<<<(E+255)/256, 256, 0, stream>>>(edge_index, curb, order, srcs, tgts, E);

  // --- weight transforms ---
  fctrans_kernel<<<((int)W3T+255)/256, 256, 0, stream>>>(rad_w3, w3h, w3l, 64, 3840);
  fctrans_kernel<<<((int)FC1+255)/256, 256, 0, stream>>>(c1_fc0_w, f1h, f1l, 1280, 896);
  fctrans_kernel<<<((int)FC2+255)/256, 256, 0, stream>>>(c2_fc0_w, f2h, f2l, 320, 640);
  for(int i=0;i<4;i++)
    wtrans_kernel<<<((int)W1S[i]*2+255)/256, 256, 0, stream>>>(c1_wm[i], w1h[i], w1l[i], K1[i], C1c[i]);
  for(int i=0;i<4;i++)
    wtrans_kernel<<<((int)W2S[i]*2+255)/256, 256, 0, stream>>>(c2_wm[i], w2h[i], w2l[i], K2[i], C2c[i]);
  ptrans_kernel<<<320, 256, 0, stream>>>(proj_w, pwt);

  auto launchM = [&](GrpArgs &ga, int gx, int gy){
    ga.gx = gx; ga.gy = gy;
    int base = gx>>3, rem = gx&7;
    int maxs = base + (rem?1:0);
    mgemm_kernel<<<8*maxs*gy, 256, 0, stream>>>(ga);
  };

  const int OFF1[4] = {5,13,19,23};
  for(int ch=0; ch<nch; ch++){
    int e0 = ch*C;
    int ce = (E - e0 < C) ? (E - e0) : C;
    int mt = (ce+127)/128;

    // radial + rad GEMM + wigner1 in two half-chunks (rad buffer is halfC)
    int half1 = (ce+1)/2;
    for(int hh=0; hh<2; hh++){
      int h0 = hh ? half1 : 0;
      int he = hh ? (ce - half1) : half1;
      if(he <= 0) continue;
      radial_kernel<<<he, 64, 0, stream>>>(edge_dist, src_table, tgt_table,
          rad_w1, rad_b1, rad_ln1_g, rad_ln1_b, rad_w2, rad_b2, rad_ln2_g, rad_ln2_b,
          atomic_nums, order + e0 + h0, srcs + e0 + h0, tgts + e0 + h0, h2h, h2l);
      {
        GrpArgs ga = {};
        ga.ng = 1; ga.M = he;
        ga.Ah[0]=h2h; ga.Al[0]=h2l; ga.Bh[0]=w3h; ga.Bl[0]=w3l;
        ga.bias[0]=rad_b3; ga.C1[0]=rad; ga.C2[0]=nullptr;
        ga.lda[0]=64; ga.K[0]=64; ga.ldc1[0]=3840; ga.ldc2[0]=0; ga.split[0]=3840;
        ga.xoff[0]=0; ga.xoff[1]=30;
        launchM(ga, 30, (he+127)/128);
      }
      wigner1_kernel<<<he, 256, 0, stream>>>(x, wigner, order + e0 + h0, srcs + e0 + h0, tgts + e0 + h0,
          rad, msg1h + (size_t)h0*6400, msg1l + (size_t)h0*6400);
    }

    // conv1 grouped: fc0 + 4 m-blocks
    {
      GrpArgs ga = {};
      ga.ng = 5; ga.M = ce;
      ga.Ah[0]=msg1h; ga.Al[0]=msg1l; ga.Bh[0]=f1h; ga.Bl[0]=f1l;
      ga.bias[0]=c1_fc0_b; ga.C1[0]=x0e; ga.C2[0]=msg2;
      ga.lda[0]=6400; ga.K[0]=1280; ga.ldc1[0]=576; ga.ldc2[0]=1600; ga.split[0]=576;
      int xo = 7;
      ga.xoff[0]=0; ga.xoff[1]=7;
      for(int i=0;i<4;i++){
        int gidx = i+1;
        ga.Ah[gidx]=msg1h + (size_t)OFF1[i]*256; ga.Al[gidx]=msg1l + (size_t)OFF1[i]*256;
        ga.Bh[gidx]=w1h[i]; ga.Bl[gidx]=w1l[i];
        ga.bias[gidx]=nullptr; ga.C1[gidx]=msg2 + OFF1[i]*64; ga.C2[gidx]=nullptr;
        ga.lda[gidx]=6400; ga.K[gidx]=2*K1[i]; ga.ldc1[gidx]=1600; ga.ldc2[gidx]=0; ga.split[gidx]=C1c[i];
        xo += C1c[i]/128;
        ga.xoff[gidx+1]=xo;
      }
      launchM(ga, xo, mt);
    }

    grid_kernel<<<ce, 64, 0, stream>>>(msg2, x0e, to_grid, from_grid, m2h, m2l);
    alpha_kernel<<<ce, 64, 0, stream>>>(x0e, alpha_ln_g, alpha_ln_b, alpha_dot, tgts + e0, exb, ssum);

    // conv2 grouped: fc0 + 4 m-blocks
    {
      GrpArgs ga = {};
      ga.ng = 5; ga.M = ce;
      ga.Ah[0]=m2h; ga.Al[0]=m2l; ga.Bh[0]=f2h; ga.Bl[0]=f2l;
      ga.bias[0]=c2_fc0_b; ga.C1[0]=msg3; ga.C2[0]=nullptr;
      ga.lda[0]=1600; ga.K[0]=320; ga.ldc1[0]=3200; ga.ldc2[0]=0; ga.split[0]=640;
      int xo = 5;
      ga.xoff[0]=0; ga.xoff[1]=5;
      for(int i=0;i<4;i++){
        int gidx = i+1;
        ga.Ah[gidx]=m2h + (size_t)OFF1[i]*64; ga.Al[gidx]=m2l + (size_t)OFF1[i]*64;
        ga.Bh[gidx]=w2h[i]; ga.Bl[gidx]=w2l[i];
        ga.bias[gidx]=nullptr; ga.C1[gidx]=msg3 + OFF1[i]*128; ga.C2[gidx]=nullptr;
        ga.lda[gidx]=1600; ga.K[gidx]=2*K2[i]; ga.ldc1[gidx]=3200; ga.ldc2[gidx]=0; ga.split[gidx]=C2c[i];
        xo += C2c[i]/128;
        ga.xoff[gidx+1]=xo;
      }
      launchM(ga, xo, mt);
    }

    agg_kernel<<<NN, 256, 0, stream>>>(wigner, msg3, exb, order, baseb, cntb, node, e0, e0+ce);
  }

  proj_kernel<<<(NN+1)/2, 256, 0, stream>>>(node, ssum, pwt, proj_b, out, NN);
}